// Round 3
// baseline (2311.536 us; speedup 1.0000x reference)
//
#include <hip/hip_runtime.h>
#include <hip/hip_bf16.h>
#include <math.h>

#define NTOK 4096
#define HDIM 768
#define FDIM 3072
#define NEXP 4
#define MAXT 36
#define TP 8

typedef __attribute__((ext_vector_type(4))) float f32x4;
typedef __attribute__((ext_vector_type(8))) short s16x8;

__device__ __forceinline__ unsigned short f2bf(float f) {
    union { float f; unsigned int u; } v; v.f = f;
    unsigned int u = v.u;
    unsigned int r = (u + 0x7fffu + ((u >> 16) & 1u)) >> 16;
    return (unsigned short)r;
}
__device__ __forceinline__ float bf2f(unsigned short u) {
    union { unsigned int u; float f; } v; v.u = ((unsigned int)u) << 16;
    return v.f;
}

// ---------------- routing: one wave per token ------------------------------------
__global__ void __launch_bounds__(256) route_kernel(
    const float* __restrict__ h, const float* __restrict__ Wsc, const float* __restrict__ bsc,
    const float* __restrict__ Wsu, const float* __restrict__ bsu,
    int* __restrict__ route_c, float* __restrict__ pmax_c,
    int* __restrict__ route_u, float* __restrict__ pmax_u,
    int* __restrict__ counts)
{
    if (blockIdx.x == 0 && threadIdx.x < 8) counts[threadIdx.x] = 0;
    int tok = blockIdx.x * 4 + (threadIdx.x >> 6);
    int lane = threadIdx.x & 63;
    const float* hr = h + (size_t)tok * HDIM;
    float ac[4] = {0.f,0.f,0.f,0.f}, au[4] = {0.f,0.f,0.f,0.f};
    for (int k = lane; k < HDIM; k += 64) {
        float x = hr[k];
        const float4 wc = *(const float4*)(Wsc + k * 4);
        const float4 wu = *(const float4*)(Wsu + k * 4);
        ac[0] += x * wc.x; ac[1] += x * wc.y; ac[2] += x * wc.z; ac[3] += x * wc.w;
        au[0] += x * wu.x; au[1] += x * wu.y; au[2] += x * wu.z; au[3] += x * wu.w;
    }
    #pragma unroll
    for (int off = 32; off > 0; off >>= 1) {
        #pragma unroll
        for (int j = 0; j < 4; ++j) {
            ac[j] += __shfl_xor(ac[j], off);
            au[j] += __shfl_xor(au[j], off);
        }
    }
    if (lane == 0) {
        float lc[4], lu[4];
        #pragma unroll
        for (int j = 0; j < 4; ++j) { lc[j] = ac[j] + bsc[j]; lu[j] = au[j] + bsu[j]; }
        int bc = 0; float mc = lc[0];
        #pragma unroll
        for (int j = 1; j < 4; ++j) if (lc[j] > mc) { mc = lc[j]; bc = j; }
        float dc = 0.f;
        #pragma unroll
        for (int j = 0; j < 4; ++j) dc += expf(lc[j] - mc);
        route_c[tok] = bc; pmax_c[tok] = 1.0f / dc;
        int bu = 0; float mu = lu[0];
        #pragma unroll
        for (int j = 1; j < 4; ++j) if (lu[j] > mu) { mu = lu[j]; bu = j; }
        float du = 0.f;
        #pragma unroll
        for (int j = 0; j < 4; ++j) du += expf(lu[j] - mu);
        route_u[tok] = bu; pmax_u[tok] = 1.0f / du;
    }
}

// ---------------- capacity-drop: rank within expert group by (-pmax, index) ------
__global__ void __launch_bounds__(256) rank_kernel(
    const int* __restrict__ rc, const float* __restrict__ pc,
    int* __restrict__ dropped, int capacity)
{
    int i = blockIdx.x, t = threadIdx.x;
    int e = rc[i]; float pi = pc[i];
    int cnt = 0;
    for (int j = t; j < NTOK; j += 256) {
        if (rc[j] == e) {
            float pj = pc[j];
            if (pj > pi || (pj == pi && j < i)) cnt++;
        }
    }
    __shared__ int red[256];
    red[t] = cnt; __syncthreads();
    for (int s = 128; s > 0; s >>= 1) {
        if (t < s) red[t] += red[t+s];
        __syncthreads();
    }
    if (t == 0) dropped[i] = (red[0] >= capacity) ? 1 : 0;
}

__global__ void __launch_bounds__(256) count_kernel(
    const int* __restrict__ rc, const int* __restrict__ ru,
    const int* __restrict__ dropped, int* __restrict__ counts)
{
    int i = blockIdx.x * 256 + threadIdx.x;
    if (i >= NTOK) return;
    atomicAdd(&counts[rc[i]], 1);
    if (dropped[i]) atomicAdd(&counts[4 + ru[i]], 1);
}

__global__ void offsets_kernel(const int* __restrict__ counts,
                               int* __restrict__ offc, int* __restrict__ offu,
                               int* __restrict__ cur, int* __restrict__ tabc)
{
    if (threadIdx.x == 0 && blockIdx.x == 0) {
        int oc = 0, ou = 0;
        for (int e = 0; e < 4; ++e) { offc[e] = oc; oc += counts[e]; }
        offc[4] = oc;
        for (int e = 0; e < 4; ++e) { offu[e] = ou; ou += counts[4+e]; }
        offu[4] = ou;
        for (int j = 0; j < 8; ++j) cur[j] = 0;
        int t = 0;
        for (int e = 0; e < 4; ++e) {
            int nt = (counts[e] + 127) >> 7;
            for (int m = 0; m < nt; ++m) { tabc[t*2] = e; tabc[t*2+1] = m; ++t; }
        }
        for (; t < MAXT; ++t) { tabc[t*2] = -1; tabc[t*2+1] = 0; }
    }
}

__global__ void __launch_bounds__(256) scatter_kernel(
    const int* __restrict__ rc, const int* __restrict__ ru, const int* __restrict__ dropped,
    const int* __restrict__ offc, const int* __restrict__ offu,
    int* __restrict__ cur, int* __restrict__ permc, int* __restrict__ permu)
{
    int i = blockIdx.x * 256 + threadIdx.x;
    if (i >= NTOK) return;
    int e = rc[i];
    int p = offc[e] + atomicAdd(&cur[e], 1);
    permc[p] = i;
    if (dropped[i]) {
        int eu = ru[i];
        int q = offu[eu] + atomicAdd(&cur[4 + eu], 1);
        permu[q] = i;
    }
}

// ---------------- gather tokens (sorted order) into bf16 (all NTOK valid) --------
__global__ void __launch_bounds__(192) gather_kernel(
    const float* __restrict__ h, const int* __restrict__ perm,
    unsigned short* __restrict__ Xs)
{
    int pos = blockIdx.x;
    int t = threadIdx.x;
    int tok = perm[pos];
    const float4 v = *(const float4*)(h + (size_t)tok * HDIM + t * 4);
    ushort4 o;
    o.x = f2bf(v.x); o.y = f2bf(v.y); o.z = f2bf(v.z); o.w = f2bf(v.w);
    *(ushort4*)(Xs + (size_t)pos * HDIM + t * 4) = o;
}

// ---------------- weight transpose+convert: fp32 [E][K][N] -> bf16 [E][N][K] -----
__global__ void __launch_bounds__(256) wtrans_kernel(
    const float* __restrict__ W, unsigned short* __restrict__ Bt, int K, int N)
{
    int e = blockIdx.z;
    const float* We = W + (size_t)e * K * N;
    unsigned short* Be = Bt + (size_t)e * N * K;
    int k0 = blockIdx.y * 32, n0 = blockIdx.x * 32;
    __shared__ float t[32][33];
    int tid = threadIdx.x;
    int r = tid >> 3, c4 = (tid & 7) * 4;
    const float4 v = *(const float4*)(We + (size_t)(k0 + r) * N + n0 + c4);
    t[r][c4+0] = v.x; t[r][c4+1] = v.y; t[r][c4+2] = v.z; t[r][c4+3] = v.w;
    __syncthreads();
    int n = tid >> 3, kk = (tid & 7) * 4;
    ushort4 o;
    o.x = f2bf(t[kk+0][n]); o.y = f2bf(t[kk+1][n]);
    o.z = f2bf(t[kk+2][n]); o.w = f2bf(t[kk+3][n]);
    *(ushort4*)(Be + (size_t)(n0 + n) * K + k0 + kk) = o;
}

// ---------------- grouped GEMM, 128x128 tile, DIRECT global->register fragments --
// No LDS, no barriers: A [rows][K] and Bt [E][N][K] are both K-contiguous, so each
// lane loads its 16x16x32 MFMA fragment with one global_load_dwordx4. 2-deep
// register pipeline keeps 8 loads in flight per wave; waves fully independent.
__global__ void __launch_bounds__(256, 3) ffn_gemm(
    const unsigned short* __restrict__ A, const unsigned short* __restrict__ Bt,
    const float* __restrict__ bias, const int* __restrict__ offs,
    const int* __restrict__ tab,
    unsigned short* __restrict__ Gout, float* __restrict__ Yout,
    const int* __restrict__ perm, int K, int N, int doGelu)
{
    int e = tab[blockIdx.y * 2];
    if (e < 0) return;
    int mt = tab[blockIdx.y * 2 + 1];
    int off = offs[e];
    int cnt = offs[e + 1] - off;
    int nt = blockIdx.x;
    int klen = K / gridDim.z;
    int kbeg = blockIdx.z * klen;
    int iters = klen >> 5;

    int tid = threadIdx.x;
    int lane = tid & 63, wave = tid >> 6;
    int wm = wave >> 1, wn = wave & 1;
    int quad = lane >> 4, l16 = lane & 15;

    const unsigned short* aptr[4];
    const unsigned short* bptr[4];
    #pragma unroll
    for (int mi = 0; mi < 4; ++mi) {
        int r = mt * 128 + wm * 64 + mi * 16 + l16;
        if (r >= cnt) r = cnt - 1;                 // dup row; masked at store
        aptr[mi] = A + (size_t)(off + r) * K + kbeg + quad * 8;
    }
    #pragma unroll
    for (int ni = 0; ni < 4; ++ni) {
        int c = nt * 128 + wn * 64 + ni * 16 + l16;
        bptr[ni] = Bt + ((size_t)e * N + c) * K + kbeg + quad * 8;
    }

    f32x4 acc[4][4];
    #pragma unroll
    for (int a = 0; a < 4; ++a)
        #pragma unroll
        for (int b = 0; b < 4; ++b)
            acc[a][b] = (f32x4){0.f, 0.f, 0.f, 0.f};

    s16x8 a0[4], b0[4], a1[4], b1[4];
    #pragma unroll
    for (int i = 0; i < 4; ++i) {
        a0[i] = *(const s16x8*)(aptr[i]);
        b0[i] = *(const s16x8*)(bptr[i]);
    }
    for (int it = 0; it < iters; it += 2) {
        if (it + 1 < iters) {
            #pragma unroll
            for (int i = 0; i < 4; ++i) {
                a1[i] = *(const s16x8*)(aptr[i] + (it + 1) * 32);
                b1[i] = *(const s16x8*)(bptr[i] + (it + 1) * 32);
            }
        }
        #pragma unroll
        for (int mi = 0; mi < 4; ++mi)
            #pragma unroll
            for (int ni = 0; ni < 4; ++ni)
                acc[mi][ni] = __builtin_amdgcn_mfma_f32_16x16x32_bf16(a0[mi], b0[ni], acc[mi][ni], 0, 0, 0);
        if (it + 2 < iters) {
            #pragma unroll
            for (int i = 0; i < 4; ++i) {
                a0[i] = *(const s16x8*)(aptr[i] + (it + 2) * 32);
                b0[i] = *(const s16x8*)(bptr[i] + (it + 2) * 32);
            }
        }
        if (it + 1 < iters) {
            #pragma unroll
            for (int mi = 0; mi < 4; ++mi)
                #pragma unroll
                for (int ni = 0; ni < 4; ++ni)
                    acc[mi][ni] = __builtin_amdgcn_mfma_f32_16x16x32_bf16(a1[mi], b1[ni], acc[mi][ni], 0, 0, 0);
        }
    }

    // epilogue: C/D layout col=lane&15, row=quad*4+reg
    #pragma unroll
    for (int ni = 0; ni < 4; ++ni) {
        int col = nt * 128 + wn * 64 + ni * 16 + l16;
        float bv = (blockIdx.z == 0) ? bias[(size_t)e * N + col] : 0.f;
        #pragma unroll
        for (int mi = 0; mi < 4; ++mi) {
            #pragma unroll
            for (int r = 0; r < 4; ++r) {
                int lm = mt * 128 + wm * 64 + mi * 16 + quad * 4 + r;
                if (lm < cnt) {
                    float x = acc[mi][ni][r] + bv;
                    if (doGelu) {
                        x = 0.5f * x * (1.0f + erff(x * 0.70710678118654752440f));
                        Gout[(size_t)(off + lm) * N + col] = f2bf(x);
                    } else {
                        atomicAdd(&Yout[(size_t)perm[off + lm] * N + col], x);
                    }
                }
            }
        }
    }
}

// ---------------- unique path: GEMV-style over the ~dozens of dropped tokens -----
// Reads W1u fp32 in native [E][K][N] layout (coalesced over n), x broadcast from LDS.
__global__ void __launch_bounds__(256) ffn1u_kernel(
    const float* __restrict__ h, const int* __restrict__ permu, const int* __restrict__ offu,
    const float* __restrict__ W1u, const float* __restrict__ b1u,
    unsigned short* __restrict__ Gu)
{
    int e = blockIdx.y;
    int beg = offu[e], end = offu[e + 1];
    if (beg >= end) return;
    int n = blockIdx.x * 256 + threadIdx.x;
    const float* We = W1u + (size_t)e * HDIM * FDIM;
    float bb = b1u[e * FDIM + n];
    __shared__ float xs[TP][HDIM];
    for (int p0 = beg; p0 < end; p0 += TP) {
        int np = min(TP, end - p0);
        __syncthreads();
        for (int t = 0; t < np; ++t) {
            const float* hr = h + (size_t)permu[p0 + t] * HDIM;
            for (int k = threadIdx.x; k < HDIM; k += 256) xs[t][k] = hr[k];
        }
        __syncthreads();
        float acc[TP];
        #pragma unroll
        for (int t = 0; t < TP; ++t) acc[t] = 0.f;
        #pragma unroll 8
        for (int k = 0; k < HDIM; ++k) {
            float wv = We[(size_t)k * FDIM + n];
            #pragma unroll
            for (int t = 0; t < TP; ++t) acc[t] += xs[t][k] * wv;
        }
        for (int t = 0; t < np; ++t) {
            float x = acc[t] + bb;
            x = 0.5f * x * (1.0f + erff(x * 0.70710678118654752440f));
            Gu[(size_t)(p0 + t) * FDIM + n] = f2bf(x);
        }
    }
}

__global__ void __launch_bounds__(256) ffn2u_kernel(
    const unsigned short* __restrict__ Gu, const int* __restrict__ permu,
    const int* __restrict__ offu,
    const float* __restrict__ W2u, const float* __restrict__ b2u,
    float* __restrict__ out)
{
    int e = blockIdx.y;
    int beg = offu[e], end = offu[e + 1];
    if (beg >= end) return;
    int n = blockIdx.x * 256 + threadIdx.x;   // 0..767
    const float* We = W2u + (size_t)e * FDIM * HDIM;
    float bb = b2u[e * HDIM + n];
    __shared__ float xs[TP][1024];
    for (int p0 = beg; p0 < end; p0 += TP) {
        int np = min(TP, end - p0);
        float acc[TP];
        #pragma unroll
        for (int t = 0; t < TP; ++t) acc[t] = 0.f;
        for (int kc = 0; kc < FDIM; kc += 1024) {
            __syncthreads();
            for (int t = 0; t < np; ++t) {
                const unsigned short* gr = Gu + (size_t)(p0 + t) * FDIM + kc;
                for (int k = threadIdx.x; k < 1024; k += 256) xs[t][k] = bf2f(gr[k]);
            }
            __syncthreads();
            #pragma unroll 8
            for (int k = 0; k < 1024; ++k) {
                float wv = We[(size_t)(kc + k) * HDIM + n];
                #pragma unroll
                for (int t = 0; t < TP; ++t) acc[t] += xs[t][k] * wv;
            }
        }
        for (int t = 0; t < np; ++t)
            atomicAdd(&out[(size_t)permu[p0 + t] * HDIM + n], acc[t] + bb);
    }
}

extern "C" void kernel_launch(void* const* d_in, const int* in_sizes, int n_in,
                              void* d_out, int out_size, void* d_ws, size_t ws_size,
                              hipStream_t stream) {
    (void)in_sizes; (void)n_in; (void)out_size; (void)ws_size;
    const float* h   = (const float*)d_in[0];
    const float* Wsc = (const float*)d_in[1];
    const float* bsc = (const float*)d_in[2];
    const float* W1c = (const float*)d_in[3];
    const float* b1c = (const float*)d_in[4];
    const float* W2c = (const float*)d_in[5];
    const float* b2c = (const float*)d_in[6];
    const float* Wsu = (const float*)d_in[7];
    const float* bsu = (const float*)d_in[8];
    const float* W1u = (const float*)d_in[9];
    const float* b1u = (const float*)d_in[10];
    const float* W2u = (const float*)d_in[11];
    const float* b2u = (const float*)d_in[12];
    float* out = (float*)d_out;

    char* w = (char*)d_ws;
    size_t o = 0;
    auto carve = [&](size_t bytes) -> char* {
        char* p = w + o; o += (bytes + 255) & ~(size_t)255; return p;
    };
    int*   route_c = (int*)carve(NTOK * 4);
    float* pmax_c  = (float*)carve(NTOK * 4);
    int*   route_u = (int*)carve(NTOK * 4);
    float* pmax_u  = (float*)carve(NTOK * 4);
    int*   dropped = (int*)carve(NTOK * 4);
    int*   counts  = (int*)carve(8 * 4);
    int*   offc    = (int*)carve(5 * 4);
    int*   offu    = (int*)carve(5 * 4);
    int*   cur     = (int*)carve(8 * 4);
    int*   permc   = (int*)carve(NTOK * 4);
    int*   permu   = (int*)carve(NTOK * 4);
    int*   tabc    = (int*)carve(MAXT * 2 * 4);
    unsigned short* Xc  = (unsigned short*)carve((size_t)NTOK * HDIM * 2);
    unsigned short* G   = (unsigned short*)carve((size_t)NTOK * FDIM * 2);
    unsigned short* Gu  = (unsigned short*)carve((size_t)NTOK * FDIM * 2);
    unsigned short* BtA = (unsigned short*)carve((size_t)NEXP * HDIM * FDIM * 2);
    unsigned short* BtB = (unsigned short*)carve((size_t)NEXP * HDIM * FDIM * 2);

    int capacity = NTOK / NEXP;   // int(1.0 * 4096 / 4) = 1024

    hipMemsetAsync(out, 0, (size_t)NTOK * HDIM * 4, stream);

    route_kernel<<<NTOK/4, 256, 0, stream>>>(h, Wsc, bsc, Wsu, bsu,
                                             route_c, pmax_c, route_u, pmax_u, counts);
    rank_kernel<<<NTOK, 256, 0, stream>>>(route_c, pmax_c, dropped, capacity);
    count_kernel<<<NTOK/256, 256, 0, stream>>>(route_c, route_u, dropped, counts);
    offsets_kernel<<<1, 64, 0, stream>>>(counts, offc, offu, cur, tabc);
    scatter_kernel<<<NTOK/256, 256, 0, stream>>>(route_c, route_u, dropped,
                                                 offc, offu, cur, permc, permu);
    gather_kernel<<<NTOK, 192, 0, stream>>>(h, permc, Xc);

    wtrans_kernel<<<dim3(FDIM/32, HDIM/32, NEXP), 256, 0, stream>>>(W1c, BtA, HDIM, FDIM);
    wtrans_kernel<<<dim3(HDIM/32, FDIM/32, NEXP), 256, 0, stream>>>(W2c, BtB, FDIM, HDIM);

    // common path
    ffn_gemm<<<dim3(FDIM/128, MAXT, 1), 256, 0, stream>>>(
        Xc, BtA, b1c, offc, tabc, G, nullptr, nullptr, HDIM, FDIM, 1);
    ffn_gemm<<<dim3(HDIM/128, MAXT, 2), 256, 0, stream>>>(
        G, BtB, b2c, offc, tabc, nullptr, out, permc, FDIM, HDIM, 0);

    // unique path (dropped tokens only), GEMV-style, accumulated into out
    ffn1u_kernel<<<dim3(FDIM/256, NEXP), 256, 0, stream>>>(h, permu, offu, W1u, b1u, Gu);
    ffn2u_kernel<<<dim3(HDIM/256, NEXP), 256, 0, stream>>>(Gu, permu, offu, W2u, b2u, out);
}

// Round 4
// 557.105 us; speedup vs baseline: 4.1492x; 4.1492x over previous
//
#include <hip/hip_runtime.h>
#include <hip/hip_bf16.h>
#include <math.h>

#define NTOK 4096
#define HDIM 768
#define FDIM 3072
#define NEXP 4
#define MAXU 3072            // worst-case dropped tokens
#define MAXT 64              // worst-case total (expert,mtile) tiles across 8 groups
#define NPOS (NTOK + MAXU)

typedef __attribute__((ext_vector_type(4))) float f32x4;
typedef __attribute__((ext_vector_type(8))) short s16x8;

__device__ __forceinline__ unsigned short f2bf(float f) {
    union { float f; unsigned int u; } v; v.f = f;
    unsigned int u = v.u;
    unsigned int r = (u + 0x7fffu + ((u >> 16) & 1u)) >> 16;
    return (unsigned short)r;
}

// ---------------- routing: one wave per token ------------------------------------
__global__ void __launch_bounds__(256) route_kernel(
    const float* __restrict__ h, const float* __restrict__ Wsc, const float* __restrict__ bsc,
    const float* __restrict__ Wsu, const float* __restrict__ bsu,
    int* __restrict__ route_c, float* __restrict__ pmax_c,
    int* __restrict__ route_u, int* __restrict__ counts)
{
    if (blockIdx.x == 0 && threadIdx.x < 8) counts[threadIdx.x] = 0;
    int tok = blockIdx.x * 4 + (threadIdx.x >> 6);
    int lane = threadIdx.x & 63;
    const float* hr = h + (size_t)tok * HDIM;
    float ac[4] = {0.f,0.f,0.f,0.f}, au[4] = {0.f,0.f,0.f,0.f};
    for (int k = lane; k < HDIM; k += 64) {
        float x = hr[k];
        const float4 wc = *(const float4*)(Wsc + k * 4);
        const float4 wu = *(const float4*)(Wsu + k * 4);
        ac[0] += x * wc.x; ac[1] += x * wc.y; ac[2] += x * wc.z; ac[3] += x * wc.w;
        au[0] += x * wu.x; au[1] += x * wu.y; au[2] += x * wu.z; au[3] += x * wu.w;
    }
    #pragma unroll
    for (int off = 32; off > 0; off >>= 1) {
        #pragma unroll
        for (int j = 0; j < 4; ++j) {
            ac[j] += __shfl_xor(ac[j], off);
            au[j] += __shfl_xor(au[j], off);
        }
    }
    if (lane == 0) {
        float lc[4], lu[4];
        #pragma unroll
        for (int j = 0; j < 4; ++j) { lc[j] = ac[j] + bsc[j]; lu[j] = au[j] + bsu[j]; }
        int bc = 0; float mc = lc[0];
        #pragma unroll
        for (int j = 1; j < 4; ++j) if (lc[j] > mc) { mc = lc[j]; bc = j; }
        float dc = 0.f;
        #pragma unroll
        for (int j = 0; j < 4; ++j) dc += expf(lc[j] - mc);
        route_c[tok] = bc; pmax_c[tok] = 1.0f / dc;
        int bu = 0; float mu = lu[0];
        #pragma unroll
        for (int j = 1; j < 4; ++j) if (lu[j] > mu) { mu = lu[j]; bu = j; }
        route_u[tok] = bu;
    }
}

// ---------------- capacity-drop: rank within expert group by (-pmax, index) ------
__global__ void __launch_bounds__(256) rank_kernel(
    const int* __restrict__ rc, const float* __restrict__ pc,
    int* __restrict__ dropped, int capacity)
{
    int i = blockIdx.x, t = threadIdx.x;
    int e = rc[i]; float pi = pc[i];
    int cnt = 0;
    for (int j = t; j < NTOK; j += 256) {
        if (rc[j] == e) {
            float pj = pc[j];
            if (pj > pi || (pj == pi && j < i)) cnt++;
        }
    }
    __shared__ int red[256];
    red[t] = cnt; __syncthreads();
    for (int s = 128; s > 0; s >>= 1) {
        if (t < s) red[t] += red[t+s];
        __syncthreads();
    }
    if (t == 0) dropped[i] = (red[0] >= capacity) ? 1 : 0;
}

__global__ void __launch_bounds__(256) count_kernel(
    const int* __restrict__ rc, const int* __restrict__ ru,
    const int* __restrict__ dropped, int* __restrict__ counts)
{
    int i = blockIdx.x * 256 + threadIdx.x;
    if (i >= NTOK) return;
    atomicAdd(&counts[rc[i]], 1);
    if (dropped[i]) atomicAdd(&counts[4 + ru[i]], 1);
}

// build combined offsets for 8 groups (4 common + 4 unique), tile table, ntot
__global__ void offsets_kernel(const int* __restrict__ counts,
                               int* __restrict__ offAll,  // 9 ints
                               int* __restrict__ cur,     // 8 ints
                               int* __restrict__ tab,     // MAXT*2
                               int* __restrict__ ntot)    // 1 int
{
    if (threadIdx.x == 0 && blockIdx.x == 0) {
        int o = 0;
        for (int e = 0; e < 8; ++e) { offAll[e] = o; o += counts[e]; }
        offAll[8] = o;
        *ntot = o;
        for (int j = 0; j < 8; ++j) cur[j] = 0;
        int t = 0;
        for (int e = 0; e < 8; ++e) {
            int nt = (counts[e] + 127) >> 7;
            for (int m = 0; m < nt && t < MAXT; ++m) { tab[t*2] = e; tab[t*2+1] = m; ++t; }
        }
        for (; t < MAXT; ++t) { tab[t*2] = -1; tab[t*2+1] = 0; }
    }
}

__global__ void __launch_bounds__(256) scatter_kernel(
    const int* __restrict__ rc, const int* __restrict__ ru, const int* __restrict__ dropped,
    const int* __restrict__ offAll, int* __restrict__ cur, int* __restrict__ perm)
{
    int i = blockIdx.x * 256 + threadIdx.x;
    if (i >= NTOK) return;
    int e = rc[i];
    int p = offAll[e] + atomicAdd(&cur[e], 1);
    perm[p] = i;
    if (dropped[i]) {
        int eu = 4 + ru[i];
        int q = offAll[eu] + atomicAdd(&cur[eu], 1);
        perm[q] = i;
    }
}

// ---------------- gather tokens (sorted order) into bf16 -------------------------
__global__ void __launch_bounds__(192) gather_kernel(
    const float* __restrict__ h, const int* __restrict__ perm,
    const int* __restrict__ ntot, unsigned short* __restrict__ Xs)
{
    int pos = blockIdx.x;
    if (pos >= *ntot) return;
    int t = threadIdx.x;
    int tok = perm[pos];
    const float4 v = *(const float4*)(h + (size_t)tok * HDIM + t * 4);
    ushort4 o;
    o.x = f2bf(v.x); o.y = f2bf(v.y); o.z = f2bf(v.z); o.w = f2bf(v.w);
    *(ushort4*)(Xs + (size_t)pos * HDIM + t * 4) = o;
}

// ---------------- weight transpose+convert: fp32 [E][K][N] -> bf16 [E][N][K] -----
__global__ void __launch_bounds__(256) wtrans_kernel(
    const float* __restrict__ W, unsigned short* __restrict__ Bt, int K, int N)
{
    int e = blockIdx.z;
    const float* We = W + (size_t)e * K * N;
    unsigned short* Be = Bt + (size_t)e * N * K;
    int k0 = blockIdx.y * 32, n0 = blockIdx.x * 32;
    __shared__ float t[32][33];
    int tid = threadIdx.x;
    int r = tid >> 3, c4 = (tid & 7) * 4;
    const float4 v = *(const float4*)(We + (size_t)(k0 + r) * N + n0 + c4);
    t[r][c4+0] = v.x; t[r][c4+1] = v.y; t[r][c4+2] = v.z; t[r][c4+3] = v.w;
    __syncthreads();
    int n = tid >> 3, kk = (tid & 7) * 4;
    ushort4 o;
    o.x = f2bf(t[kk+0][n]); o.y = f2bf(t[kk+1][n]);
    o.z = f2bf(t[kk+2][n]); o.w = f2bf(t[kk+3][n]);
    *(ushort4*)(Be + (size_t)(n0 + n) * K + k0 + kk) = o;
}

// ---------------- grouped GEMM over 8 expert groups, 128x128 tile ----------------
// Direct global->register MFMA fragments (K-contiguous on both operands).
__global__ void __launch_bounds__(256, 3) ffn_gemm(
    const unsigned short* __restrict__ A, const unsigned short* __restrict__ Bt,
    const float* __restrict__ bias, const int* __restrict__ offs,
    const int* __restrict__ tab,
    unsigned short* __restrict__ Gout, float* __restrict__ Yout,
    const int* __restrict__ perm, int K, int N, int doGelu)
{
    int e = tab[blockIdx.y * 2];
    if (e < 0) return;
    int mt = tab[blockIdx.y * 2 + 1];
    int off = offs[e];
    int cnt = offs[e + 1] - off;
    if (mt * 128 >= cnt) return;
    int nt = blockIdx.x;
    int klen = K / gridDim.z;
    int kbeg = blockIdx.z * klen;
    int iters = klen >> 5;

    int tid = threadIdx.x;
    int lane = tid & 63, wave = tid >> 6;
    int wm = wave >> 1, wn = wave & 1;
    int quad = lane >> 4, l16 = lane & 15;

    const unsigned short* aptr[4];
    const unsigned short* bptr[4];
    #pragma unroll
    for (int mi = 0; mi < 4; ++mi) {
        int r = mt * 128 + wm * 64 + mi * 16 + l16;
        if (r >= cnt) r = cnt - 1;                 // dup row; masked at store
        aptr[mi] = A + (size_t)(off + r) * K + kbeg + quad * 8;
    }
    #pragma unroll
    for (int ni = 0; ni < 4; ++ni) {
        int c = nt * 128 + wn * 64 + ni * 16 + l16;
        bptr[ni] = Bt + ((size_t)e * N + c) * K + kbeg + quad * 8;
    }

    f32x4 acc[4][4];
    #pragma unroll
    for (int a = 0; a < 4; ++a)
        #pragma unroll
        for (int b = 0; b < 4; ++b)
            acc[a][b] = (f32x4){0.f, 0.f, 0.f, 0.f};

    s16x8 a0[4], b0[4], a1[4], b1[4];
    #pragma unroll
    for (int i = 0; i < 4; ++i) {
        a0[i] = *(const s16x8*)(aptr[i]);
        b0[i] = *(const s16x8*)(bptr[i]);
    }
    for (int it = 0; it < iters; it += 2) {
        if (it + 1 < iters) {
            #pragma unroll
            for (int i = 0; i < 4; ++i) {
                a1[i] = *(const s16x8*)(aptr[i] + (it + 1) * 32);
                b1[i] = *(const s16x8*)(bptr[i] + (it + 1) * 32);
            }
        }
        #pragma unroll
        for (int mi = 0; mi < 4; ++mi)
            #pragma unroll
            for (int ni = 0; ni < 4; ++ni)
                acc[mi][ni] = __builtin_amdgcn_mfma_f32_16x16x32_bf16(a0[mi], b0[ni], acc[mi][ni], 0, 0, 0);
        if (it + 2 < iters) {
            #pragma unroll
            for (int i = 0; i < 4; ++i) {
                a0[i] = *(const s16x8*)(aptr[i] + (it + 2) * 32);
                b0[i] = *(const s16x8*)(bptr[i] + (it + 2) * 32);
            }
        }
        if (it + 1 < iters) {
            #pragma unroll
            for (int mi = 0; mi < 4; ++mi)
                #pragma unroll
                for (int ni = 0; ni < 4; ++ni)
                    acc[mi][ni] = __builtin_amdgcn_mfma_f32_16x16x32_bf16(a1[mi], b1[ni], acc[mi][ni], 0, 0, 0);
        }
    }

    // epilogue: C/D layout col=lane&15, row=quad*4+reg
    #pragma unroll
    for (int ni = 0; ni < 4; ++ni) {
        int col = nt * 128 + wn * 64 + ni * 16 + l16;
        float bv = (blockIdx.z == 0) ? bias[(size_t)e * N + col] : 0.f;
        #pragma unroll
        for (int mi = 0; mi < 4; ++mi) {
            #pragma unroll
            for (int r = 0; r < 4; ++r) {
                int lm = mt * 128 + wm * 64 + mi * 16 + quad * 4 + r;
                if (lm < cnt) {
                    float x = acc[mi][ni][r] + bv;
                    if (doGelu) {
                        x = 0.5f * x * (1.0f + erff(x * 0.70710678118654752440f));
                        Gout[(size_t)(off + lm) * N + col] = f2bf(x);
                    } else {
                        atomicAdd(&Yout[(size_t)perm[off + lm] * N + col], x);
                    }
                }
            }
        }
    }
}

extern "C" void kernel_launch(void* const* d_in, const int* in_sizes, int n_in,
                              void* d_out, int out_size, void* d_ws, size_t ws_size,
                              hipStream_t stream) {
    (void)in_sizes; (void)n_in; (void)out_size; (void)ws_size;
    const float* h   = (const float*)d_in[0];
    const float* Wsc = (const float*)d_in[1];
    const float* bsc = (const float*)d_in[2];
    const float* W1c = (const float*)d_in[3];
    const float* b1c = (const float*)d_in[4];
    const float* W2c = (const float*)d_in[5];
    const float* b2c = (const float*)d_in[6];
    const float* Wsu = (const float*)d_in[7];
    const float* bsu = (const float*)d_in[8];
    const float* W1u = (const float*)d_in[9];
    const float* b1u = (const float*)d_in[10];
    const float* W2u = (const float*)d_in[11];
    const float* b2u = (const float*)d_in[12];
    float* out = (float*)d_out;

    char* w = (char*)d_ws;
    size_t o = 0;
    auto carve = [&](size_t bytes) -> char* {
        char* p = w + o; o += (bytes + 255) & ~(size_t)255; return p;
    };
    int*   route_c = (int*)carve(NTOK * 4);
    float* pmax_c  = (float*)carve(NTOK * 4);
    int*   route_u = (int*)carve(NTOK * 4);
    int*   dropped = (int*)carve(NTOK * 4);
    int*   counts  = (int*)carve(8 * 4);
    int*   offAll  = (int*)carve(9 * 4);
    int*   cur     = (int*)carve(8 * 4);
    int*   ntot    = (int*)carve(4);
    int*   perm    = (int*)carve(NPOS * 4);
    int*   tab     = (int*)carve(MAXT * 2 * 4);
    float* bias1   = (float*)carve(8 * FDIM * 4);
    float* bias2   = (float*)carve(8 * HDIM * 4);
    unsigned short* X   = (unsigned short*)carve((size_t)NPOS * HDIM * 2);
    unsigned short* G   = (unsigned short*)carve((size_t)NPOS * FDIM * 2);
    unsigned short* BtA = (unsigned short*)carve((size_t)8 * HDIM * FDIM * 2);
    unsigned short* BtB = (unsigned short*)carve((size_t)8 * FDIM * HDIM * 2);

    int capacity = NTOK / NEXP;   // int(1.0 * 4096 / 4) = 1024

    hipMemsetAsync(out, 0, (size_t)NTOK * HDIM * 4, stream);
    hipMemcpyAsync(bias1,            b1c, (size_t)NEXP * FDIM * 4, hipMemcpyDeviceToDevice, stream);
    hipMemcpyAsync(bias1 + 4 * FDIM, b1u, (size_t)NEXP * FDIM * 4, hipMemcpyDeviceToDevice, stream);
    hipMemcpyAsync(bias2,            b2c, (size_t)NEXP * HDIM * 4, hipMemcpyDeviceToDevice, stream);
    hipMemcpyAsync(bias2 + 4 * HDIM, b2u, (size_t)NEXP * HDIM * 4, hipMemcpyDeviceToDevice, stream);

    route_kernel<<<NTOK/4, 256, 0, stream>>>(h, Wsc, bsc, Wsu, bsu,
                                             route_c, pmax_c, route_u, counts);
    rank_kernel<<<NTOK, 256, 0, stream>>>(route_c, pmax_c, dropped, capacity);
    count_kernel<<<NTOK/256, 256, 0, stream>>>(route_c, route_u, dropped, counts);
    offsets_kernel<<<1, 64, 0, stream>>>(counts, offAll, cur, tab, ntot);
    scatter_kernel<<<NTOK/256, 256, 0, stream>>>(route_c, route_u, dropped,
                                                 offAll, cur, perm);
    gather_kernel<<<NPOS, 192, 0, stream>>>(h, perm, ntot, X);

    // transpose+convert all 8 expert matrices per layer into bf16 [8][N][K]
    wtrans_kernel<<<dim3(FDIM/32, HDIM/32, NEXP), 256, 0, stream>>>(W1c, BtA, HDIM, FDIM);
    wtrans_kernel<<<dim3(FDIM/32, HDIM/32, NEXP), 256, 0, stream>>>(
        W1u, BtA + (size_t)4 * HDIM * FDIM, HDIM, FDIM);
    wtrans_kernel<<<dim3(HDIM/32, FDIM/32, NEXP), 256, 0, stream>>>(W2c, BtB, FDIM, HDIM);
    wtrans_kernel<<<dim3(HDIM/32, FDIM/32, NEXP), 256, 0, stream>>>(
        W2u, BtB + (size_t)4 * FDIM * HDIM, FDIM, HDIM);

    // unified FFN over 8 groups
    ffn_gemm<<<dim3(FDIM/128, MAXT, 1), 256, 0, stream>>>(
        X, BtA, bias1, offAll, tab, G, nullptr, nullptr, HDIM, FDIM, 1);
    ffn_gemm<<<dim3(HDIM/128, MAXT, 2), 256, 0, stream>>>(
        G, BtB, bias2, offAll, tab, nullptr, out, perm, FDIM, HDIM, 0);
}

// Round 5
// 417.126 us; speedup vs baseline: 5.5416x; 1.3356x over previous
//
#include <hip/hip_runtime.h>
#include <hip/hip_bf16.h>
#include <math.h>

#define NTOK 4096
#define HDIM 768
#define FDIM 3072
#define NEXP 4
#define MAXU 3072            // worst-case dropped tokens
#define MAXT 64              // worst-case (expert,mtile) tiles across 8 groups
#define NPOS (NTOK + MAXU)

typedef __attribute__((ext_vector_type(4))) float f32x4;
typedef __attribute__((ext_vector_type(8))) short s16x8;

__device__ __forceinline__ unsigned short f2bf(float f) {
    union { float f; unsigned int u; } v; v.f = f;
    unsigned int u = v.u;
    unsigned int r = (u + 0x7fffu + ((u >> 16) & 1u)) >> 16;
    return (unsigned short)r;
}

// async global->LDS, 16B per lane. lds dst is wave-uniform; HW adds lane*16.
__device__ __forceinline__ void gload_lds16(const unsigned short* g, unsigned short* l) {
    __builtin_amdgcn_global_load_lds((const __attribute__((address_space(1))) void*)g,
                                     (__attribute__((address_space(3))) void*)l, 16, 0, 0);
}

// ---------------- routing: one wave per token ------------------------------------
__global__ void __launch_bounds__(256) route_kernel(
    const float* __restrict__ h, const float* __restrict__ Wsc, const float* __restrict__ bsc,
    const float* __restrict__ Wsu, const float* __restrict__ bsu,
    int* __restrict__ route_c, float* __restrict__ pmax_c,
    int* __restrict__ route_u, int* __restrict__ counts)
{
    if (blockIdx.x == 0 && threadIdx.x < 8) counts[threadIdx.x] = 0;
    int tok = blockIdx.x * 4 + (threadIdx.x >> 6);
    int lane = threadIdx.x & 63;
    const float* hr = h + (size_t)tok * HDIM;
    float ac[4] = {0.f,0.f,0.f,0.f}, au[4] = {0.f,0.f,0.f,0.f};
    for (int k = lane; k < HDIM; k += 64) {
        float x = hr[k];
        const float4 wc = *(const float4*)(Wsc + k * 4);
        const float4 wu = *(const float4*)(Wsu + k * 4);
        ac[0] += x * wc.x; ac[1] += x * wc.y; ac[2] += x * wc.z; ac[3] += x * wc.w;
        au[0] += x * wu.x; au[1] += x * wu.y; au[2] += x * wu.z; au[3] += x * wu.w;
    }
    #pragma unroll
    for (int off = 32; off > 0; off >>= 1) {
        #pragma unroll
        for (int j = 0; j < 4; ++j) {
            ac[j] += __shfl_xor(ac[j], off);
            au[j] += __shfl_xor(au[j], off);
        }
    }
    if (lane == 0) {
        float lc[4], lu[4];
        #pragma unroll
        for (int j = 0; j < 4; ++j) { lc[j] = ac[j] + bsc[j]; lu[j] = au[j] + bsu[j]; }
        int bc = 0; float mc = lc[0];
        #pragma unroll
        for (int j = 1; j < 4; ++j) if (lc[j] > mc) { mc = lc[j]; bc = j; }
        float dc = 0.f;
        #pragma unroll
        for (int j = 0; j < 4; ++j) dc += expf(lc[j] - mc);
        route_c[tok] = bc; pmax_c[tok] = 1.0f / dc;
        int bu = 0; float mu = lu[0];
        #pragma unroll
        for (int j = 1; j < 4; ++j) if (lu[j] > mu) { mu = lu[j]; bu = j; }
        route_u[tok] = bu;
    }
}

// ---------------- capacity-drop: rank within expert group by (-pmax, index) ------
__global__ void __launch_bounds__(256) rank_kernel(
    const int* __restrict__ rc, const float* __restrict__ pc,
    int* __restrict__ dropped, int capacity)
{
    int i = blockIdx.x, t = threadIdx.x;
    int e = rc[i]; float pi = pc[i];
    int cnt = 0;
    for (int j = t; j < NTOK; j += 256) {
        if (rc[j] == e) {
            float pj = pc[j];
            if (pj > pi || (pj == pi && j < i)) cnt++;
        }
    }
    __shared__ int red[256];
    red[t] = cnt; __syncthreads();
    for (int s = 128; s > 0; s >>= 1) {
        if (t < s) red[t] += red[t+s];
        __syncthreads();
    }
    if (t == 0) dropped[i] = (red[0] >= capacity) ? 1 : 0;
}

__global__ void __launch_bounds__(256) count_kernel(
    const int* __restrict__ rc, const int* __restrict__ ru,
    const int* __restrict__ dropped, int* __restrict__ counts)
{
    int i = blockIdx.x * 256 + threadIdx.x;
    if (i >= NTOK) return;
    atomicAdd(&counts[rc[i]], 1);
    if (dropped[i]) atomicAdd(&counts[4 + ru[i]], 1);
}

// offsets for 8 groups (4 common + 4 unique), tile table, ntot
__global__ void offsets_kernel(const int* __restrict__ counts,
                               int* __restrict__ offAll,  // 9
                               int* __restrict__ cur,     // 8
                               int* __restrict__ tab,     // MAXT*2
                               int* __restrict__ ntot)
{
    if (threadIdx.x == 0 && blockIdx.x == 0) {
        int o = 0;
        for (int e = 0; e < 8; ++e) { offAll[e] = o; o += counts[e]; }
        offAll[8] = o;
        *ntot = o;
        for (int j = 0; j < 8; ++j) cur[j] = 0;
        int t = 0;
        for (int e = 0; e < 8; ++e) {
            int nt = (counts[e] + 127) >> 7;
            for (int m = 0; m < nt && t < MAXT; ++m) { tab[t*2] = e; tab[t*2+1] = m; ++t; }
        }
        for (; t < MAXT; ++t) { tab[t*2] = -1; tab[t*2+1] = 0; }
    }
}

__global__ void __launch_bounds__(256) scatter_kernel(
    const int* __restrict__ rc, const int* __restrict__ ru, const int* __restrict__ dropped,
    const int* __restrict__ offAll, int* __restrict__ cur, int* __restrict__ perm,
    int* __restrict__ invC, int* __restrict__ invU)
{
    int i = blockIdx.x * 256 + threadIdx.x;
    if (i >= NTOK) return;
    int e = rc[i];
    int p = offAll[e] + atomicAdd(&cur[e], 1);
    perm[p] = i;
    invC[i] = p;
    if (dropped[i]) {
        int eu = 4 + ru[i];
        int q = offAll[eu] + atomicAdd(&cur[eu], 1);
        perm[q] = i;
        invU[i] = q;
    }
}

// ---------------- gather tokens (sorted order) into bf16 -------------------------
__global__ void __launch_bounds__(192) gather_kernel(
    const float* __restrict__ h, const int* __restrict__ perm,
    const int* __restrict__ ntot, unsigned short* __restrict__ Xs)
{
    int pos = blockIdx.x;
    if (pos >= *ntot) return;
    int t = threadIdx.x;
    int tok = perm[pos];
    const float4 v = *(const float4*)(h + (size_t)tok * HDIM + t * 4);
    ushort4 o;
    o.x = f2bf(v.x); o.y = f2bf(v.y); o.z = f2bf(v.z); o.w = f2bf(v.w);
    *(ushort4*)(Xs + (size_t)pos * HDIM + t * 4) = o;
}

// ---------------- weight transpose+convert: fp32 [E][K][N] -> bf16 [E][N][K] -----
__global__ void __launch_bounds__(256) wtrans_kernel(
    const float* __restrict__ W, unsigned short* __restrict__ Bt, int K, int N)
{
    int e = blockIdx.z;
    const float* We = W + (size_t)e * K * N;
    unsigned short* Be = Bt + (size_t)e * N * K;
    int k0 = blockIdx.y * 32, n0 = blockIdx.x * 32;
    __shared__ float t[32][33];
    int tid = threadIdx.x;
    int r = tid >> 3, c4 = (tid & 7) * 4;
    const float4 v = *(const float4*)(We + (size_t)(k0 + r) * N + n0 + c4);
    t[r][c4+0] = v.x; t[r][c4+1] = v.y; t[r][c4+2] = v.z; t[r][c4+3] = v.w;
    __syncthreads();
    int n = tid >> 3, kk = (tid & 7) * 4;
    ushort4 o;
    o.x = f2bf(t[kk+0][n]); o.y = f2bf(t[kk+1][n]);
    o.z = f2bf(t[kk+2][n]); o.w = f2bf(t[kk+3][n]);
    *(ushort4*)(Be + (size_t)(n0 + n) * K + k0 + kk) = o;
}

// ---------------- grouped GEMM over 8 expert groups, 128x128 tile ----------------
// LDS staging via global_load_lds (round-2 K-loop, lowest FETCH), clean epilogues:
//  doGelu=1: GELU -> wave-private LDS repack -> ushort4 full-line stores to Gout[pos]
//  doGelu=0: fp32 full-line stores into per-z slab Yout[z][pos][N] (no atomics)
__global__ void __launch_bounds__(256) ffn_gemm(
    const unsigned short* __restrict__ A, const unsigned short* __restrict__ Bt,
    const float* __restrict__ bias, const int* __restrict__ offs,
    const int* __restrict__ tab,
    unsigned short* __restrict__ Gout, float* __restrict__ Yout,
    int K, int N, int doGelu)
{
    int e = tab[blockIdx.y * 2];
    if (e < 0) return;
    int mt = tab[blockIdx.y * 2 + 1];
    int off = offs[e];
    int cnt = offs[e + 1] - off;
    if (mt * 128 >= cnt) return;
    int nt = blockIdx.x;
    int klen = K / gridDim.z;
    int kbeg = blockIdx.z * klen, kend = kbeg + klen;

    // 17408 shorts = 34816 B. Staging: As=[0,4096), Bs=[8704,12800).
    // Epilogue repack: wave w uses [w*4352, w*4352+4352) (64 rows x stride 68).
    __shared__ unsigned short lds[17408];
    unsigned short* As = lds;
    unsigned short* Bs = lds + 8704;

    int tid = threadIdx.x;
    int lane = tid & 63, wave = tid >> 6;
    int wm = wave >> 1, wn = wave & 1;
    int quad = lane >> 4, l16 = lane & 15;

    f32x4 acc[4][4];
    #pragma unroll
    for (int a = 0; a < 4; ++a)
        #pragma unroll
        for (int b = 0; b < 4; ++b)
            acc[a][b] = (f32x4){0.f, 0.f, 0.f, 0.f};

    // staging: 512 16B-chunks per tile; thread handles chunks tid and tid+256.
    int r0 = tid >> 2, s0 = tid & 3;
    int r1 = (tid + 256) >> 2;
    int seg0 = (s0 ^ ((r0 & 3) ^ ((r0 >> 2) & 3))) * 8;
    int seg1 = (s0 ^ ((r1 & 3) ^ ((r1 >> 2) & 3))) * 8;
    int ar0 = mt * 128 + r0; if (ar0 >= cnt) ar0 = cnt - 1;
    int ar1 = mt * 128 + r1; if (ar1 >= cnt) ar1 = cnt - 1;

    const unsigned short* Ae = A + (size_t)off * K;
    const unsigned short* Be = Bt + ((size_t)e * N + (size_t)nt * 128) * K;
    const unsigned short* asrc0 = Ae + (size_t)ar0 * K + seg0;
    const unsigned short* asrc1 = Ae + (size_t)ar1 * K + seg1;
    const unsigned short* bsrc0 = Be + (size_t)r0 * K + seg0;
    const unsigned short* bsrc1 = Be + (size_t)r1 * K + seg1;
    unsigned short* al0 = &As[wave * 512];
    unsigned short* al1 = &As[2048 + wave * 512];
    unsigned short* bl0 = &Bs[wave * 512];
    unsigned short* bl1 = &Bs[2048 + wave * 512];

    int cca = quad ^ ((l16 & 3) ^ ((l16 >> 2) & 3));

    for (int k0 = kbeg; k0 < kend; k0 += 32) {
        gload_lds16(asrc0 + k0, al0);
        gload_lds16(asrc1 + k0, al1);
        gload_lds16(bsrc0 + k0, bl0);
        gload_lds16(bsrc1 + k0, bl1);
        __syncthreads();

        s16x8 af[4], bf[4];
        #pragma unroll
        for (int mi = 0; mi < 4; ++mi)
            af[mi] = *(const s16x8*)&As[(wm * 64 + mi * 16 + l16) * 32 + cca * 8];
        #pragma unroll
        for (int ni = 0; ni < 4; ++ni)
            bf[ni] = *(const s16x8*)&Bs[(wn * 64 + ni * 16 + l16) * 32 + cca * 8];
        #pragma unroll
        for (int mi = 0; mi < 4; ++mi)
            #pragma unroll
            for (int ni = 0; ni < 4; ++ni)
                acc[mi][ni] = __builtin_amdgcn_mfma_f32_16x16x32_bf16(af[mi], bf[ni], acc[mi][ni], 0, 0, 0);
        __syncthreads();
    }

    if (doGelu) {
        // GELU + bf16, repack 64x64 wave tile via wave-private LDS, 8B/lane stores
        unsigned short* R = lds + wave * 4352;   // 64 rows, stride 68 shorts
        #pragma unroll
        for (int ni = 0; ni < 4; ++ni) {
            int col = nt * 128 + wn * 64 + ni * 16 + l16;
            float bv = bias[(size_t)e * N + col];
            #pragma unroll
            for (int mi = 0; mi < 4; ++mi) {
                #pragma unroll
                for (int r = 0; r < 4; ++r) {
                    float x = acc[mi][ni][r] + bv;
                    x = 0.5f * x * (1.0f + erff(x * 0.70710678118654752440f));
                    R[(mi * 16 + quad * 4 + r) * 68 + ni * 16 + l16] = f2bf(x);
                }
            }
        }
        __builtin_amdgcn_s_waitcnt(0);  // drain lgkm for wave-private LDS
        int lrow = lane >> 4, lcol = (lane & 15) * 4;
        #pragma unroll
        for (int p = 0; p < 16; ++p) {
            int row = p * 4 + lrow;
            int gr = mt * 128 + wm * 64 + row;
            if (gr < cnt) {
                ushort4 v = *(const ushort4*)&R[row * 68 + lcol];
                *(ushort4*)&Gout[(size_t)(off + gr) * N + nt * 128 + wn * 64 + lcol] = v;
            }
        }
    } else {
        float* Yz = Yout + (size_t)blockIdx.z * NPOS * N;
        #pragma unroll
        for (int ni = 0; ni < 4; ++ni) {
            int col = nt * 128 + wn * 64 + ni * 16 + l16;
            float bv = (blockIdx.z == 0) ? bias[(size_t)e * N + col] : 0.f;
            #pragma unroll
            for (int mi = 0; mi < 4; ++mi) {
                #pragma unroll
                for (int r = 0; r < 4; ++r) {
                    int lm = mt * 128 + wm * 64 + mi * 16 + quad * 4 + r;
                    if (lm < cnt)
                        Yz[(size_t)(off + lm) * N + col] = acc[mi][ni][r] + bv;
                }
            }
        }
    }
}

// ---------------- combine: out[tok] = sum_z Y[z][posC] + dropped * sum_z Y[z][posU]
__global__ void __launch_bounds__(192) combine_kernel(
    const float* __restrict__ Y, const int* __restrict__ invC,
    const int* __restrict__ invU, const int* __restrict__ dropped,
    float* __restrict__ out)
{
    int tok = blockIdx.x, t = threadIdx.x;
    const float* Y0 = Y;
    const float* Y1 = Y + (size_t)NPOS * HDIM;
    int pc = invC[tok];
    float4 a = *(const float4*)(Y0 + (size_t)pc * HDIM + t * 4);
    float4 b = *(const float4*)(Y1 + (size_t)pc * HDIM + t * 4);
    float4 o;
    o.x = a.x + b.x; o.y = a.y + b.y; o.z = a.z + b.z; o.w = a.w + b.w;
    if (dropped[tok]) {
        int pu = invU[tok];
        float4 c = *(const float4*)(Y0 + (size_t)pu * HDIM + t * 4);
        float4 d = *(const float4*)(Y1 + (size_t)pu * HDIM + t * 4);
        o.x += c.x + d.x; o.y += c.y + d.y; o.z += c.z + d.z; o.w += c.w + d.w;
    }
    *(float4*)(out + (size_t)tok * HDIM + t * 4) = o;
}

extern "C" void kernel_launch(void* const* d_in, const int* in_sizes, int n_in,
                              void* d_out, int out_size, void* d_ws, size_t ws_size,
                              hipStream_t stream) {
    (void)in_sizes; (void)n_in; (void)out_size; (void)ws_size;
    const float* h   = (const float*)d_in[0];
    const float* Wsc = (const float*)d_in[1];
    const float* bsc = (const float*)d_in[2];
    const float* W1c = (const float*)d_in[3];
    const float* b1c = (const float*)d_in[4];
    const float* W2c = (const float*)d_in[5];
    const float* b2c = (const float*)d_in[6];
    const float* Wsu = (const float*)d_in[7];
    const float* bsu = (const float*)d_in[8];
    const float* W1u = (const float*)d_in[9];
    const float* b1u = (const float*)d_in[10];
    const float* W2u = (const float*)d_in[11];
    const float* b2u = (const float*)d_in[12];
    float* out = (float*)d_out;

    char* w = (char*)d_ws;
    size_t o = 0;
    auto carve = [&](size_t bytes) -> char* {
        char* p = w + o; o += (bytes + 255) & ~(size_t)255; return p;
    };
    int*   route_c = (int*)carve(NTOK * 4);
    float* pmax_c  = (float*)carve(NTOK * 4);
    int*   route_u = (int*)carve(NTOK * 4);
    int*   dropped = (int*)carve(NTOK * 4);
    int*   counts  = (int*)carve(8 * 4);
    int*   offAll  = (int*)carve(9 * 4);
    int*   cur     = (int*)carve(8 * 4);
    int*   ntot    = (int*)carve(4);
    int*   perm    = (int*)carve(NPOS * 4);
    int*   invC    = (int*)carve(NTOK * 4);
    int*   invU    = (int*)carve(NTOK * 4);
    int*   tab     = (int*)carve(MAXT * 2 * 4);
    float* bias1   = (float*)carve(8 * FDIM * 4);
    float* bias2   = (float*)carve(8 * HDIM * 4);
    unsigned short* X   = (unsigned short*)carve((size_t)NPOS * HDIM * 2);
    unsigned short* G   = (unsigned short*)carve((size_t)NPOS * FDIM * 2);
    float*          Y2  = (float*)carve((size_t)2 * NPOS * HDIM * 4);
    unsigned short* BtA = (unsigned short*)carve((size_t)8 * HDIM * FDIM * 2);
    unsigned short* BtB = (unsigned short*)carve((size_t)8 * FDIM * HDIM * 2);

    int capacity = NTOK / NEXP;   // int(1.0 * 4096 / 4) = 1024

    hipMemcpyAsync(bias1,            b1c, (size_t)NEXP * FDIM * 4, hipMemcpyDeviceToDevice, stream);
    hipMemcpyAsync(bias1 + 4 * FDIM, b1u, (size_t)NEXP * FDIM * 4, hipMemcpyDeviceToDevice, stream);
    hipMemcpyAsync(bias2,            b2c, (size_t)NEXP * HDIM * 4, hipMemcpyDeviceToDevice, stream);
    hipMemcpyAsync(bias2 + 4 * HDIM, b2u, (size_t)NEXP * HDIM * 4, hipMemcpyDeviceToDevice, stream);

    route_kernel<<<NTOK/4, 256, 0, stream>>>(h, Wsc, bsc, Wsu, bsu,
                                             route_c, pmax_c, route_u, counts);
    rank_kernel<<<NTOK, 256, 0, stream>>>(route_c, pmax_c, dropped, capacity);
    count_kernel<<<NTOK/256, 256, 0, stream>>>(route_c, route_u, dropped, counts);
    offsets_kernel<<<1, 64, 0, stream>>>(counts, offAll, cur, tab, ntot);
    scatter_kernel<<<NTOK/256, 256, 0, stream>>>(route_c, route_u, dropped,
                                                 offAll, cur, perm, invC, invU);
    gather_kernel<<<NPOS, 192, 0, stream>>>(h, perm, ntot, X);

    // transpose+convert all 8 expert matrices per layer into bf16 [8][N][K]
    wtrans_kernel<<<dim3(FDIM/32, HDIM/32, NEXP), 256, 0, stream>>>(W1c, BtA, HDIM, FDIM);
    wtrans_kernel<<<dim3(FDIM/32, HDIM/32, NEXP), 256, 0, stream>>>(
        W1u, BtA + (size_t)4 * HDIM * FDIM, HDIM, FDIM);
    wtrans_kernel<<<dim3(HDIM/32, FDIM/32, NEXP), 256, 0, stream>>>(W2c, BtB, FDIM, HDIM);
    wtrans_kernel<<<dim3(HDIM/32, FDIM/32, NEXP), 256, 0, stream>>>(
        W2u, BtB + (size_t)4 * FDIM * HDIM, FDIM, HDIM);

    // FFN1 over 8 groups: X @ W1 -> GELU -> G (bf16, position-indexed)
    ffn_gemm<<<dim3(FDIM/128, MAXT, 1), 256, 0, stream>>>(
        X, BtA, bias1, offAll, tab, G, nullptr, HDIM, FDIM, 1);
    // FFN2: G @ W2 -> Y2[z][pos][H] (fp32 slabs, split-K=2, no atomics)
    ffn_gemm<<<dim3(HDIM/128, MAXT, 2), 256, 0, stream>>>(
        G, BtB, bias2, offAll, tab, nullptr, Y2, FDIM, HDIM, 0);
    // out[tok] = sum of slabs at common pos (+ unique pos if dropped)
    combine_kernel<<<NTOK, 192, 0, stream>>>(Y2, invC, invU, dropped, out);
}

// Round 7
// 410.859 us; speedup vs baseline: 5.6261x; 1.0153x over previous
//
#include <hip/hip_runtime.h>
#include <hip/hip_bf16.h>
#include <math.h>

#define NTOK 4096
#define HDIM 768
#define FDIM 3072
#define NEXP 4
#define MAXU 3072            // worst-case dropped tokens
#define MAXT 64              // worst-case (expert,mtile) tiles across 8 groups
#define NPOS (NTOK + MAXU)
#define RSTRIDE 76           // repack LDS row stride (shorts): quad bank-bases disjoint

typedef __attribute__((ext_vector_type(4))) float f32x4;
typedef __attribute__((ext_vector_type(8))) short s16x8;

__device__ __forceinline__ unsigned short f2bf(float f) {
    union { float f; unsigned int u; } v; v.f = f;
    unsigned int u = v.u;
    unsigned int r = (u + 0x7fffu + ((u >> 16) & 1u)) >> 16;
    return (unsigned short)r;
}

// async global->LDS, 16B per lane. lds dst is wave-uniform; HW adds lane*16.
__device__ __forceinline__ void gload_lds16(const unsigned short* g, unsigned short* l) {
    __builtin_amdgcn_global_load_lds((const __attribute__((address_space(1))) void*)g,
                                     (__attribute__((address_space(3))) void*)l, 16, 0, 0);
}

// ---------------- routing: one wave per token ------------------------------------
__global__ void __launch_bounds__(256) route_kernel(
    const float* __restrict__ h, const float* __restrict__ Wsc, const float* __restrict__ bsc,
    const float* __restrict__ Wsu, const float* __restrict__ bsu,
    int* __restrict__ route_c, float* __restrict__ pmax_c,
    int* __restrict__ route_u, int* __restrict__ counts)
{
    if (blockIdx.x == 0 && threadIdx.x < 8) counts[threadIdx.x] = 0;
    int tok = blockIdx.x * 4 + (threadIdx.x >> 6);
    int lane = threadIdx.x & 63;
    const float* hr = h + (size_t)tok * HDIM;
    float ac[4] = {0.f,0.f,0.f,0.f}, au[4] = {0.f,0.f,0.f,0.f};
    for (int k = lane; k < HDIM; k += 64) {
        float x = hr[k];
        const float4 wc = *(const float4*)(Wsc + k * 4);
        const float4 wu = *(const float4*)(Wsu + k * 4);
        ac[0] += x * wc.x; ac[1] += x * wc.y; ac[2] += x * wc.z; ac[3] += x * wc.w;
        au[0] += x * wu.x; au[1] += x * wu.y; au[2] += x * wu.z; au[3] += x * wu.w;
    }
    #pragma unroll
    for (int off = 32; off > 0; off >>= 1) {
        #pragma unroll
        for (int j = 0; j < 4; ++j) {
            ac[j] += __shfl_xor(ac[j], off);
            au[j] += __shfl_xor(au[j], off);
        }
    }
    if (lane == 0) {
        float lc[4], lu[4];
        #pragma unroll
        for (int j = 0; j < 4; ++j) { lc[j] = ac[j] + bsc[j]; lu[j] = au[j] + bsu[j]; }
        int bc = 0; float mc = lc[0];
        #pragma unroll
        for (int j = 1; j < 4; ++j) if (lc[j] > mc) { mc = lc[j]; bc = j; }
        float dc = 0.f;
        #pragma unroll
        for (int j = 0; j < 4; ++j) dc += expf(lc[j] - mc);
        route_c[tok] = bc; pmax_c[tok] = 1.0f / dc;
        int bu = 0; float mu = lu[0];
        #pragma unroll
        for (int j = 1; j < 4; ++j) if (lu[j] > mu) { mu = lu[j]; bu = j; }
        route_u[tok] = bu;
    }
}

// ---------------- rank within expert group by (-pmax, index); fused histogram ----
__global__ void __launch_bounds__(256) rank_kernel(
    const int* __restrict__ rc, const int* __restrict__ ru,
    const float* __restrict__ pc,
    int* __restrict__ dropped, int* __restrict__ counts, int capacity)
{
    int i = blockIdx.x, t = threadIdx.x;
    int e = rc[i]; float pi = pc[i];
    int cnt = 0;
    for (int j = t; j < NTOK; j += 256) {
        if (rc[j] == e) {
            float pj = pc[j];
            if (pj > pi || (pj == pi && j < i)) cnt++;
        }
    }
    __shared__ int red[256];
    red[t] = cnt; __syncthreads();
    for (int s = 128; s > 0; s >>= 1) {
        if (t < s) red[t] += red[t+s];
        __syncthreads();
    }
    if (t == 0) {
        int d = (red[0] >= capacity) ? 1 : 0;
        dropped[i] = d;
        atomicAdd(&counts[e], 1);
        if (d) atomicAdd(&counts[4 + ru[i]], 1);
    }
}

// offsets for 8 groups (4 common + 4 unique), tile table, ntot
__global__ void offsets_kernel(const int* __restrict__ counts,
                               int* __restrict__ offAll,  // 9
                               int* __restrict__ cur,     // 8
                               int* __restrict__ tab,     // MAXT*2
                               int* __restrict__ ntot)
{
    if (threadIdx.x == 0 && blockIdx.x == 0) {
        int o = 0;
        for (int e = 0; e < 8; ++e) { offAll[e] = o; o += counts[e]; }
        offAll[8] = o;
        *ntot = o;
        for (int j = 0; j < 8; ++j) cur[j] = 0;
        int t = 0;
        for (int e = 0; e < 8; ++e) {
            int nt = (counts[e] + 127) >> 7;
            for (int m = 0; m < nt && t < MAXT; ++m) { tab[t*2] = e; tab[t*2+1] = m; ++t; }
        }
        for (; t < MAXT; ++t) { tab[t*2] = -1; tab[t*2+1] = 0; }
    }
}

__global__ void __launch_bounds__(256) scatter_kernel(
    const int* __restrict__ rc, const int* __restrict__ ru, const int* __restrict__ dropped,
    const int* __restrict__ offAll, int* __restrict__ cur, int* __restrict__ perm,
    int* __restrict__ invC, int* __restrict__ invU)
{
    int i = blockIdx.x * 256 + threadIdx.x;
    if (i >= NTOK) return;
    int e = rc[i];
    int p = offAll[e] + atomicAdd(&cur[e], 1);
    perm[p] = i;
    invC[i] = p;
    if (dropped[i]) {
        int eu = 4 + ru[i];
        int q = offAll[eu] + atomicAdd(&cur[eu], 1);
        perm[q] = i;
        invU[i] = q;
    }
}

// ---------------- gather tokens (sorted order) into bf16 -------------------------
__global__ void __launch_bounds__(192) gather_kernel(
    const float* __restrict__ h, const int* __restrict__ perm,
    const int* __restrict__ ntot, unsigned short* __restrict__ Xs)
{
    int pos = blockIdx.x;
    if (pos >= *ntot) return;
    int t = threadIdx.x;
    int tok = perm[pos];
    const float4 v = *(const float4*)(h + (size_t)tok * HDIM + t * 4);
    ushort4 o;
    o.x = f2bf(v.x); o.y = f2bf(v.y); o.z = f2bf(v.z); o.w = f2bf(v.w);
    *(ushort4*)(Xs + (size_t)pos * HDIM + t * 4) = o;
}

// ------------- weight transpose+convert: fp32 [4][K][N] x2 -> bf16 [8][N][K] -----
__global__ void __launch_bounds__(256) wtrans_kernel(
    const float* __restrict__ Wc, const float* __restrict__ Wu,
    unsigned short* __restrict__ Bt, int K, int N)
{
    int z = blockIdx.z;   // 0..7
    const float* We = (z < 4) ? (Wc + (size_t)z * K * N)
                              : (Wu + (size_t)(z - 4) * K * N);
    unsigned short* Be = Bt + (size_t)z * N * K;
    int k0 = blockIdx.y * 64, n0 = blockIdx.x * 64;
    __shared__ float t[64][65];
    int tid = threadIdx.x;
    int rr = tid >> 4, cc = (tid & 15) * 4;
    #pragma unroll
    for (int i = 0; i < 4; ++i) {
        int row = rr + i * 16;
        const float4 v = *(const float4*)(We + (size_t)(k0 + row) * N + n0 + cc);
        t[row][cc+0] = v.x; t[row][cc+1] = v.y; t[row][cc+2] = v.z; t[row][cc+3] = v.w;
    }
    __syncthreads();
    #pragma unroll
    for (int i = 0; i < 4; ++i) {
        int n = rr + i * 16;
        ushort4 o;
        o.x = f2bf(t[cc+0][n]); o.y = f2bf(t[cc+1][n]);
        o.z = f2bf(t[cc+2][n]); o.w = f2bf(t[cc+3][n]);
        *(ushort4*)(Be + (size_t)(n0 + n) * K + k0 + cc) = o;
    }
}

// ---------------- grouped GEMM over 8 groups, 128(M)x64(N) tile ------------------
// LDS staging via global_load_lds; wave tile 32x64, acc[2][4].
//  doGelu=1: GELU -> wave-private LDS repack -> ushort4 full-line stores to Gout[pos]
//  doGelu=0: fp32 stores into per-z slab Yout[z][pos][N] (no atomics)
__global__ void __launch_bounds__(256, 4) ffn_gemm(
    const unsigned short* __restrict__ A, const unsigned short* __restrict__ Bt,
    const float* __restrict__ biasC, const float* __restrict__ biasU,
    const int* __restrict__ offs, const int* __restrict__ tab,
    unsigned short* __restrict__ Gout, float* __restrict__ Yout,
    int K, int N, int doGelu)
{
    int e = tab[blockIdx.y * 2];
    if (e < 0) return;
    int mt = tab[blockIdx.y * 2 + 1];
    int off = offs[e];
    int cnt = offs[e + 1] - off;
    if (mt * 128 >= cnt) return;
    int nt = blockIdx.x;
    int klen = K / gridDim.z;
    int kbeg = blockIdx.z * klen, kend = kbeg + klen;

    // LDS: staging A [0,4096) shorts (128r x 32k), B [4096,6144) (64r x 32k);
    // epilogue repack reuses [0, 4*32*RSTRIDE) = 9728 shorts.
    __shared__ unsigned short lds[9728];
    unsigned short* As = lds;
    unsigned short* Bs = lds + 4096;

    int tid = threadIdx.x;
    int lane = tid & 63, wave = tid >> 6;
    int quad = lane >> 4, l16 = lane & 15;

    f32x4 acc[2][4];
    #pragma unroll
    for (int a = 0; a < 2; ++a)
        #pragma unroll
        for (int b = 0; b < 4; ++b)
            acc[a][b] = (f32x4){0.f, 0.f, 0.f, 0.f};

    // staging: A 512 chunks (thread: tid, tid+256), B 256 chunks (thread: tid)
    int r0 = tid >> 2, s0 = tid & 3;
    int r1 = (tid + 256) >> 2;
    int seg0 = (s0 ^ ((r0 & 3) ^ ((r0 >> 2) & 3))) * 8;
    int seg1 = (s0 ^ ((r1 & 3) ^ ((r1 >> 2) & 3))) * 8;
    int ar0 = mt * 128 + r0; if (ar0 >= cnt) ar0 = cnt - 1;
    int ar1 = mt * 128 + r1; if (ar1 >= cnt) ar1 = cnt - 1;

    const unsigned short* Ae = A + (size_t)off * K;
    const unsigned short* Be = Bt + ((size_t)e * N + (size_t)nt * 64) * K;
    const unsigned short* asrc0 = Ae + (size_t)ar0 * K + seg0;
    const unsigned short* asrc1 = Ae + (size_t)ar1 * K + seg1;
    const unsigned short* bsrc0 = Be + (size_t)r0 * K + seg0;   // B rows 0..63
    // chunk c (8 shorts) lives at As[c*8]; wave w covers chunks w*64+lane (al0)
    // and 256+w*64+lane (al1)  [round-6 bug was *1024 scaling — overwrote Bs]
    unsigned short* al0 = &As[wave * 512];
    unsigned short* al1 = &As[2048 + wave * 512];
    unsigned short* bl0 = &Bs[wave * 512];
    int cca = quad ^ ((l16 & 3) ^ ((l16 >> 2) & 3));

    for (int k0 = kbeg; k0 < kend; k0 += 32) {
        gload_lds16(asrc0 + k0, al0);
        gload_lds16(asrc1 + k0, al1);
        gload_lds16(bsrc0 + k0, bl0);
        __syncthreads();

        s16x8 af[2], bf[4];
        #pragma unroll
        for (int mi = 0; mi < 2; ++mi)
            af[mi] = *(const s16x8*)&As[(wave * 32 + mi * 16 + l16) * 32 + cca * 8];
        #pragma unroll
        for (int ni = 0; ni < 4; ++ni)
            bf[ni] = *(const s16x8*)&Bs[(ni * 16 + l16) * 32 + cca * 8];
        #pragma unroll
        for (int mi = 0; mi < 2; ++mi)
            #pragma unroll
            for (int ni = 0; ni < 4; ++ni)
                acc[mi][ni] = __builtin_amdgcn_mfma_f32_16x16x32_bf16(af[mi], bf[ni], acc[mi][ni], 0, 0, 0);
        __syncthreads();
    }

    const float* bias = (e < 4) ? (biasC + (size_t)e * N) : (biasU + (size_t)(e - 4) * N);

    if (doGelu) {
        // GELU + bf16, repack 32x64 wave tile via wave-private LDS, 8B/lane stores
        unsigned short* R = lds + wave * (32 * RSTRIDE);
        #pragma unroll
        for (int ni = 0; ni < 4; ++ni) {
            float bv = bias[nt * 64 + ni * 16 + l16];
            #pragma unroll
            for (int mi = 0; mi < 2; ++mi) {
                #pragma unroll
                for (int r = 0; r < 4; ++r) {
                    float x = acc[mi][ni][r] + bv;
                    x = 0.5f * x * (1.0f + erff(x * 0.70710678118654752440f));
                    R[(mi * 16 + quad * 4 + r) * RSTRIDE + ni * 16 + l16] = f2bf(x);
                }
            }
        }
        __builtin_amdgcn_s_waitcnt(0);  // wave-private region: no barrier needed
        int lrow = lane >> 4, lcol = (lane & 15) * 4;
        #pragma unroll
        for (int p = 0; p < 8; ++p) {
            int row = p * 4 + lrow;
            int gr = mt * 128 + wave * 32 + row;
            if (gr < cnt) {
                ushort4 v = *(const ushort4*)&R[row * RSTRIDE + lcol];
                *(ushort4*)&Gout[(size_t)(off + gr) * N + nt * 64 + lcol] = v;
            }
        }
    } else {
        float* Yz = Yout + (size_t)blockIdx.z * NPOS * N;
        #pragma unroll
        for (int ni = 0; ni < 4; ++ni) {
            int col = nt * 64 + ni * 16 + l16;
            float bv = (blockIdx.z == 0) ? bias[col] : 0.f;
            #pragma unroll
            for (int mi = 0; mi < 2; ++mi) {
                #pragma unroll
                for (int r = 0; r < 4; ++r) {
                    int lm = mt * 128 + wave * 32 + mi * 16 + quad * 4 + r;
                    if (lm < cnt)
                        Yz[(size_t)(off + lm) * N + col] = acc[mi][ni][r] + bv;
                }
            }
        }
    }
}

// ---------------- combine: out[tok] = sum_z Y[z][posC] + dropped * sum_z Y[z][posU]
__global__ void __launch_bounds__(192) combine_kernel(
    const float* __restrict__ Y, const int* __restrict__ invC,
    const int* __restrict__ invU, const int* __restrict__ dropped,
    float* __restrict__ out)
{
    int tok = blockIdx.x, t = threadIdx.x;
    const float* Y0 = Y;
    const float* Y1 = Y + (size_t)NPOS * HDIM;
    int pc = invC[tok];
    float4 a = *(const float4*)(Y0 + (size_t)pc * HDIM + t * 4);
    float4 b = *(const float4*)(Y1 + (size_t)pc * HDIM + t * 4);
    float4 o;
    o.x = a.x + b.x; o.y = a.y + b.y; o.z = a.z + b.z; o.w = a.w + b.w;
    if (dropped[tok]) {
        int pu = invU[tok];
        float4 c = *(const float4*)(Y0 + (size_t)pu * HDIM + t * 4);
        float4 d = *(const float4*)(Y1 + (size_t)pu * HDIM + t * 4);
        o.x += c.x + d.x; o.y += c.y + d.y; o.z += c.z + d.z; o.w += c.w + d.w;
    }
    *(float4*)(out + (size_t)tok * HDIM + t * 4) = o;
}

extern "C" void kernel_launch(void* const* d_in, const int* in_sizes, int n_in,
                              void* d_out, int out_size, void* d_ws, size_t ws_size,
                              hipStream_t stream) {
    (void)in_sizes; (void)n_in; (void)out_size; (void)ws_size;
    const float* h   = (const float*)d_in[0];
    const float* Wsc = (const float*)d_in[1];
    const float* bsc = (const float*)d_in[2];
    const float* W1c = (const float*)d_in[3];
    const float* b1c = (const float*)d_in[4];
    const float* W2c = (const float*)d_in[5];
    const float* b2c = (const float*)d_in[6];
    const float* Wsu = (const float*)d_in[7];
    const float* bsu = (const float*)d_in[8];
    const float* W1u = (const float*)d_in[9];
    const float* b1u = (const float*)d_in[10];
    const float* W2u = (const float*)d_in[11];
    const float* b2u = (const float*)d_in[12];
    float* out = (float*)d_out;

    char* w = (char*)d_ws;
    size_t o = 0;
    auto carve = [&](size_t bytes) -> char* {
        char* p = w + o; o += (bytes + 255) & ~(size_t)255; return p;
    };
    int*   route_c = (int*)carve(NTOK * 4);
    float* pmax_c  = (float*)carve(NTOK * 4);
    int*   route_u = (int*)carve(NTOK * 4);
    int*   dropped = (int*)carve(NTOK * 4);
    int*   counts  = (int*)carve(8 * 4);
    int*   offAll  = (int*)carve(9 * 4);
    int*   cur     = (int*)carve(8 * 4);
    int*   ntot    = (int*)carve(4);
    int*   perm    = (int*)carve(NPOS * 4);
    int*   invC    = (int*)carve(NTOK * 4);
    int*   invU    = (int*)carve(NTOK * 4);
    int*   tab     = (int*)carve(MAXT * 2 * 4);
    unsigned short* X   = (unsigned short*)carve((size_t)NPOS * HDIM * 2);
    unsigned short* G   = (unsigned short*)carve((size_t)NPOS * FDIM * 2);
    float*          Y2  = (float*)carve((size_t)2 * NPOS * HDIM * 4);
    unsigned short* BtA = (unsigned short*)carve((size_t)8 * HDIM * FDIM * 2);
    unsigned short* BtB = (unsigned short*)carve((size_t)8 * FDIM * HDIM * 2);

    int capacity = NTOK / NEXP;   // int(1.0 * 4096 / 4) = 1024

    route_kernel<<<NTOK/4, 256, 0, stream>>>(h, Wsc, bsc, Wsu, bsu,
                                             route_c, pmax_c, route_u, counts);
    rank_kernel<<<NTOK, 256, 0, stream>>>(route_c, route_u, pmax_c,
                                          dropped, counts, capacity);
    offsets_kernel<<<1, 64, 0, stream>>>(counts, offAll, cur, tab, ntot);
    scatter_kernel<<<NTOK/256, 256, 0, stream>>>(route_c, route_u, dropped,
                                                 offAll, cur, perm, invC, invU);
    gather_kernel<<<NPOS, 192, 0, stream>>>(h, perm, ntot, X);

    // transpose+convert weights to bf16 [8][N][K] (c experts z<4, u experts z>=4)
    wtrans_kernel<<<dim3(FDIM/64, HDIM/64, 8), 256, 0, stream>>>(W1c, W1u, BtA, HDIM, FDIM);
    wtrans_kernel<<<dim3(HDIM/64, FDIM/64, 8), 256, 0, stream>>>(W2c, W2u, BtB, FDIM, HDIM);

    // FFN1 over 8 groups: X @ W1 -> GELU -> G (bf16, position-indexed)
    ffn_gemm<<<dim3(FDIM/64, MAXT, 1), 256, 0, stream>>>(
        X, BtA, b1c, b1u, offAll, tab, G, nullptr, HDIM, FDIM, 1);
    // FFN2: G @ W2 -> Y2[z][pos][H] (fp32 slabs, split-K=2, no atomics)
    ffn_gemm<<<dim3(HDIM/64, MAXT, 2), 256, 0, stream>>>(
        G, BtB, b2c, b2u, offAll, tab, nullptr, Y2, FDIM, HDIM, 0);
    // out[tok] = sum of slabs at common pos (+ unique pos if dropped)
    combine_kernel<<<NTOK, 192, 0, stream>>>(Y2, invC, invU, dropped, out);
}

// Round 8
// 404.998 us; speedup vs baseline: 5.7075x; 1.0145x over previous
//
#include <hip/hip_runtime.h>
#include <hip/hip_bf16.h>
#include <math.h>

#define NTOK 4096
#define HDIM 768
#define FDIM 3072
#define NEXP 4
#define MAXU 3072            // worst-case dropped tokens
#define MAXT 64              // worst-case (expert,mtile) tiles across 8 groups
#define NPOS (NTOK + MAXU)
#define RSTRIDE 76           // repack LDS row stride (shorts): quad bank-bases disjoint

typedef __attribute__((ext_vector_type(4))) float f32x4;
typedef __attribute__((ext_vector_type(8))) short s16x8;

__device__ __forceinline__ unsigned short f2bf(float f) {
    union { float f; unsigned int u; } v; v.f = f;
    unsigned int u = v.u;
    unsigned int r = (u + 0x7fffu + ((u >> 16) & 1u)) >> 16;
    return (unsigned short)r;
}

// async global->LDS, 16B per lane. lds dst is wave-uniform; HW adds lane*16.
__device__ __forceinline__ void gload_lds16(const unsigned short* g, unsigned short* l) {
    __builtin_amdgcn_global_load_lds((const __attribute__((address_space(1))) void*)g,
                                     (__attribute__((address_space(3))) void*)l, 16, 0, 0);
}

// ---------------- routing: one wave per token ------------------------------------
__global__ void __launch_bounds__(256) route_kernel(
    const float* __restrict__ h, const float* __restrict__ Wsc, const float* __restrict__ bsc,
    const float* __restrict__ Wsu, const float* __restrict__ bsu,
    int* __restrict__ route_c, float* __restrict__ pmax_c,
    int* __restrict__ route_u, int* __restrict__ counts)
{
    if (blockIdx.x == 0 && threadIdx.x < 8) counts[threadIdx.x] = 0;
    int tok = blockIdx.x * 4 + (threadIdx.x >> 6);
    int lane = threadIdx.x & 63;
    const float* hr = h + (size_t)tok * HDIM;
    float ac[4] = {0.f,0.f,0.f,0.f}, au[4] = {0.f,0.f,0.f,0.f};
    for (int k = lane; k < HDIM; k += 64) {
        float x = hr[k];
        const float4 wc = *(const float4*)(Wsc + k * 4);
        const float4 wu = *(const float4*)(Wsu + k * 4);
        ac[0] += x * wc.x; ac[1] += x * wc.y; ac[2] += x * wc.z; ac[3] += x * wc.w;
        au[0] += x * wu.x; au[1] += x * wu.y; au[2] += x * wu.z; au[3] += x * wu.w;
    }
    #pragma unroll
    for (int off = 32; off > 0; off >>= 1) {
        #pragma unroll
        for (int j = 0; j < 4; ++j) {
            ac[j] += __shfl_xor(ac[j], off);
            au[j] += __shfl_xor(au[j], off);
        }
    }
    if (lane == 0) {
        float lc[4], lu[4];
        #pragma unroll
        for (int j = 0; j < 4; ++j) { lc[j] = ac[j] + bsc[j]; lu[j] = au[j] + bsu[j]; }
        int bc = 0; float mc = lc[0];
        #pragma unroll
        for (int j = 1; j < 4; ++j) if (lc[j] > mc) { mc = lc[j]; bc = j; }
        float dc = 0.f;
        #pragma unroll
        for (int j = 0; j < 4; ++j) dc += expf(lc[j] - mc);
        route_c[tok] = bc; pmax_c[tok] = 1.0f / dc;
        int bu = 0; float mu = lu[0];
        #pragma unroll
        for (int j = 1; j < 4; ++j) if (lu[j] > mu) { mu = lu[j]; bu = j; }
        route_u[tok] = bu;
    }
}

// ------- rank within expert group by (-pmax, index); one WAVE per token ----------
__global__ void __launch_bounds__(256) rank_kernel(
    const int* __restrict__ rc, const int* __restrict__ ru,
    const float* __restrict__ pc,
    int* __restrict__ dropped, int* __restrict__ counts, int capacity)
{
    int wave = threadIdx.x >> 6, lane = threadIdx.x & 63;
    int i = blockIdx.x * 4 + wave;
    int e = rc[i]; float pi = pc[i];
    int cnt = 0;
    for (int j = lane; j < NTOK; j += 64) {
        if (rc[j] == e) {
            float pj = pc[j];
            if (pj > pi || (pj == pi && j < i)) cnt++;
        }
    }
    #pragma unroll
    for (int off = 32; off > 0; off >>= 1) cnt += __shfl_xor(cnt, off);
    if (lane == 0) {
        int d = (cnt >= capacity) ? 1 : 0;
        dropped[i] = d;
        atomicAdd(&counts[e], 1);
        if (d) atomicAdd(&counts[4 + ru[i]], 1);
    }
}

// offsets for 8 groups (4 common + 4 unique), tile table, ntot
__global__ void offsets_kernel(const int* __restrict__ counts,
                               int* __restrict__ offAll,  // 9
                               int* __restrict__ cur,     // 8
                               int* __restrict__ tab,     // MAXT*2
                               int* __restrict__ ntot)
{
    if (threadIdx.x == 0 && blockIdx.x == 0) {
        int o = 0;
        for (int e = 0; e < 8; ++e) { offAll[e] = o; o += counts[e]; }
        offAll[8] = o;
        *ntot = o;
        for (int j = 0; j < 8; ++j) cur[j] = 0;
        int t = 0;
        for (int e = 0; e < 8; ++e) {
            int nt = (counts[e] + 127) >> 7;
            for (int m = 0; m < nt && t < MAXT; ++m) { tab[t*2] = e; tab[t*2+1] = m; ++t; }
        }
        for (; t < MAXT; ++t) { tab[t*2] = -1; tab[t*2+1] = 0; }
    }
}

__global__ void __launch_bounds__(256) scatter_kernel(
    const int* __restrict__ rc, const int* __restrict__ ru, const int* __restrict__ dropped,
    const int* __restrict__ offAll, int* __restrict__ cur, int* __restrict__ perm,
    int* __restrict__ invC, int* __restrict__ invU)
{
    int i = blockIdx.x * 256 + threadIdx.x;
    if (i >= NTOK) return;
    int e = rc[i];
    int p = offAll[e] + atomicAdd(&cur[e], 1);
    perm[p] = i;
    invC[i] = p;
    if (dropped[i]) {
        int eu = 4 + ru[i];
        int q = offAll[eu] + atomicAdd(&cur[eu], 1);
        perm[q] = i;
        invU[i] = q;
    }
}

// ---------------- gather tokens (sorted order) into bf16 -------------------------
__global__ void __launch_bounds__(192) gather_kernel(
    const float* __restrict__ h, const int* __restrict__ perm,
    const int* __restrict__ ntot, unsigned short* __restrict__ Xs)
{
    int pos = blockIdx.x;
    if (pos >= *ntot) return;
    int t = threadIdx.x;
    int tok = perm[pos];
    const float4 v = *(const float4*)(h + (size_t)tok * HDIM + t * 4);
    ushort4 o;
    o.x = f2bf(v.x); o.y = f2bf(v.y); o.z = f2bf(v.z); o.w = f2bf(v.w);
    *(ushort4*)(Xs + (size_t)pos * HDIM + t * 4) = o;
}

// ------- weight transpose+convert: fp32 [4][K][N] x2 -> bf16 [8][N][K] -----------
// 128k x 64n tile: reads float4 coalesced, writes 256-B contiguous k-segments.
__global__ void __launch_bounds__(256) wtrans_kernel(
    const float* __restrict__ Wc, const float* __restrict__ Wu,
    unsigned short* __restrict__ Bt, int K, int N)
{
    int z = blockIdx.z;   // 0..7
    const float* We = (z < 4) ? (Wc + (size_t)z * K * N)
                              : (Wu + (size_t)(z - 4) * K * N);
    unsigned short* Be = Bt + (size_t)z * N * K;
    int k0 = blockIdx.y * 128, n0 = blockIdx.x * 64;
    __shared__ float t[128][65];
    int tid = threadIdx.x;
    int rr = tid >> 4, c4 = (tid & 15) * 4;   // 16 float4 per 64-float row
    #pragma unroll
    for (int i = 0; i < 8; ++i) {
        int row = rr + i * 16;
        const float4 v = *(const float4*)(We + (size_t)(k0 + row) * N + n0 + c4);
        t[row][c4+0] = v.x; t[row][c4+1] = v.y; t[row][c4+2] = v.z; t[row][c4+3] = v.w;
    }
    __syncthreads();
    #pragma unroll
    for (int i = 0; i < 8; ++i) {
        int idx = tid + i * 256;
        int n = idx >> 5, kk = (idx & 31) * 4;   // 32 ushort4 per 128-k row
        ushort4 o;
        o.x = f2bf(t[kk+0][n]); o.y = f2bf(t[kk+1][n]);
        o.z = f2bf(t[kk+2][n]); o.w = f2bf(t[kk+3][n]);
        *(ushort4*)(Be + (size_t)(n0 + n) * K + k0 + kk) = o;
    }
}

// ---------------- grouped GEMM over 8 groups, 128(M)x64(N), BK=64 ----------------
// LDS staging via global_load_lds, 3-bit XOR chunk swizzle; wave tile 32x64.
//  doGelu=1: GELU -> wave-private LDS repack -> ushort4 full-line stores to Gout[pos]
//  doGelu=0: fp32 stores into per-z slab Yout[z][pos][N] (no atomics)
__global__ void __launch_bounds__(256, 4) ffn_gemm(
    const unsigned short* __restrict__ A, const unsigned short* __restrict__ Bt,
    const float* __restrict__ biasC, const float* __restrict__ biasU,
    const int* __restrict__ offs, const int* __restrict__ tab,
    unsigned short* __restrict__ Gout, float* __restrict__ Yout,
    int K, int N, int doGelu)
{
    int e = tab[blockIdx.y * 2];
    if (e < 0) return;
    int mt = tab[blockIdx.y * 2 + 1];
    int off = offs[e];
    int cnt = offs[e + 1] - off;
    if (mt * 128 >= cnt) return;
    int nt = blockIdx.x;
    int klen = K / gridDim.z;
    int kbeg = blockIdx.z * klen;

    // LDS: As 128r x 64k bf16 = [0,8192) shorts; Bs 64r x 64k = [8192,12288).
    // chunk (row,s) s=0..7 holds global k-seg (s ^ (row&7)); chunk c at base c*8.
    // FFN1 epilogue repack reuses [0, 4*32*RSTRIDE)=9728 shorts.
    __shared__ unsigned short lds[12288];
    unsigned short* As = lds;
    unsigned short* Bs = lds + 8192;

    int tid = threadIdx.x;
    int lane = tid & 63, wave = tid >> 6;
    int quad = lane >> 4, l16 = lane & 15;

    f32x4 acc[2][4];
    #pragma unroll
    for (int a = 0; a < 2; ++a)
        #pragma unroll
        for (int b = 0; b < 4; ++b)
            acc[a][b] = (f32x4){0.f, 0.f, 0.f, 0.f};

    const unsigned short* Ae = A + (size_t)off * K;
    const unsigned short* Be = Bt + ((size_t)e * N + (size_t)nt * 64) * K;

    // A: 1024 chunks, 4 per thread; B: 512 chunks, 2 per thread
    const unsigned short* asrc[4]; unsigned short* adst[4];
    #pragma unroll
    for (int j = 0; j < 4; ++j) {
        int c = tid + j * 256;
        int row = c >> 3, s = c & 7;
        int gseg = (s ^ (row & 7)) * 8;
        int ar = mt * 128 + row; if (ar >= cnt) ar = cnt - 1;
        asrc[j] = Ae + (size_t)ar * K + kbeg + gseg;
        adst[j] = &As[(j * 256 + wave * 64) * 8];   // wave-uniform; HW adds lane*16B
    }
    const unsigned short* bsrc[2]; unsigned short* bdst[2];
    #pragma unroll
    for (int j = 0; j < 2; ++j) {
        int c = tid + j * 256;
        int row = c >> 3, s = c & 7;
        int gseg = (s ^ (row & 7)) * 8;
        bsrc[j] = Be + (size_t)row * K + kbeg + gseg;
        bdst[j] = &Bs[(j * 256 + wave * 64) * 8];
    }

    for (int k0 = 0; k0 < klen; k0 += 64) {
        #pragma unroll
        for (int j = 0; j < 4; ++j) gload_lds16(asrc[j] + k0, adst[j]);
        #pragma unroll
        for (int j = 0; j < 2; ++j) gload_lds16(bsrc[j] + k0, bdst[j]);
        __syncthreads();

        #pragma unroll
        for (int ks = 0; ks < 2; ++ks) {
            int cc = ((ks * 4 + quad) ^ (l16 & 7)) * 8;
            s16x8 af[2], bf[4];
            #pragma unroll
            for (int mi = 0; mi < 2; ++mi)
                af[mi] = *(const s16x8*)&As[(wave * 32 + mi * 16 + l16) * 64 + cc];
            #pragma unroll
            for (int ni = 0; ni < 4; ++ni)
                bf[ni] = *(const s16x8*)&Bs[(ni * 16 + l16) * 64 + cc];
            #pragma unroll
            for (int mi = 0; mi < 2; ++mi)
                #pragma unroll
                for (int ni = 0; ni < 4; ++ni)
                    acc[mi][ni] = __builtin_amdgcn_mfma_f32_16x16x32_bf16(af[mi], bf[ni], acc[mi][ni], 0, 0, 0);
        }
        __syncthreads();
    }

    const float* bias = (e < 4) ? (biasC + (size_t)e * N) : (biasU + (size_t)(e - 4) * N);

    if (doGelu) {
        // GELU + bf16, repack 32x64 wave tile via wave-private LDS, 8B/lane stores
        unsigned short* R = lds + wave * (32 * RSTRIDE);
        #pragma unroll
        for (int ni = 0; ni < 4; ++ni) {
            float bv = bias[nt * 64 + ni * 16 + l16];
            #pragma unroll
            for (int mi = 0; mi < 2; ++mi) {
                #pragma unroll
                for (int r = 0; r < 4; ++r) {
                    float x = acc[mi][ni][r] + bv;
                    x = 0.5f * x * (1.0f + erff(x * 0.70710678118654752440f));
                    R[(mi * 16 + quad * 4 + r) * RSTRIDE + ni * 16 + l16] = f2bf(x);
                }
            }
        }
        __builtin_amdgcn_s_waitcnt(0);  // wave-private region: no barrier needed
        int lrow = lane >> 4, lcol = (lane & 15) * 4;
        #pragma unroll
        for (int p = 0; p < 8; ++p) {
            int row = p * 4 + lrow;
            int gr = mt * 128 + wave * 32 + row;
            if (gr < cnt) {
                ushort4 v = *(const ushort4*)&R[row * RSTRIDE + lcol];
                *(ushort4*)&Gout[(size_t)(off + gr) * N + nt * 64 + lcol] = v;
            }
        }
    } else {
        float* Yz = Yout + (size_t)blockIdx.z * NPOS * N;
        #pragma unroll
        for (int ni = 0; ni < 4; ++ni) {
            int col = nt * 64 + ni * 16 + l16;
            float bv = (blockIdx.z == 0) ? bias[col] : 0.f;
            #pragma unroll
            for (int mi = 0; mi < 2; ++mi) {
                #pragma unroll
                for (int r = 0; r < 4; ++r) {
                    int lm = mt * 128 + wave * 32 + mi * 16 + quad * 4 + r;
                    if (lm < cnt)
                        Yz[(size_t)(off + lm) * N + col] = acc[mi][ni][r] + bv;
                }
            }
        }
    }
}

// ---------------- combine: out[tok] = sum_z Y[z][posC] + dropped * sum_z Y[z][posU]
__global__ void __launch_bounds__(192) combine_kernel(
    const float* __restrict__ Y, const int* __restrict__ invC,
    const int* __restrict__ invU, const int* __restrict__ dropped,
    float* __restrict__ out)
{
    int tok = blockIdx.x, t = threadIdx.x;
    const float* Y0 = Y;
    const float* Y1 = Y + (size_t)NPOS * HDIM;
    int pc = invC[tok];
    float4 a = *(const float4*)(Y0 + (size_t)pc * HDIM + t * 4);
    float4 b = *(const float4*)(Y1 + (size_t)pc * HDIM + t * 4);
    float4 o;
    o.x = a.x + b.x; o.y = a.y + b.y; o.z = a.z + b.z; o.w = a.w + b.w;
    if (dropped[tok]) {
        int pu = invU[tok];
        float4 c = *(const float4*)(Y0 + (size_t)pu * HDIM + t * 4);
        float4 d = *(const float4*)(Y1 + (size_t)pu * HDIM + t * 4);
        o.x += c.x + d.x; o.y += c.y + d.y; o.z += c.z + d.z; o.w += c.w + d.w;
    }
    *(float4*)(out + (size_t)tok * HDIM + t * 4) = o;
}

extern "C" void kernel_launch(void* const* d_in, const int* in_sizes, int n_in,
                              void* d_out, int out_size, void* d_ws, size_t ws_size,
                              hipStream_t stream) {
    (void)in_sizes; (void)n_in; (void)out_size; (void)ws_size;
    const float* h   = (const float*)d_in[0];
    const float* Wsc = (const float*)d_in[1];
    const float* bsc = (const float*)d_in[2];
    const float* W1c = (const float*)d_in[3];
    const float* b1c = (const float*)d_in[4];
    const float* W2c = (const float*)d_in[5];
    const float* b2c = (const float*)d_in[6];
    const float* Wsu = (const float*)d_in[7];
    const float* bsu = (const float*)d_in[8];
    const float* W1u = (const float*)d_in[9];
    const float* b1u = (const float*)d_in[10];
    const float* W2u = (const float*)d_in[11];
    const float* b2u = (const float*)d_in[12];
    float* out = (float*)d_out;

    char* w = (char*)d_ws;
    size_t o = 0;
    auto carve = [&](size_t bytes) -> char* {
        char* p = w + o; o += (bytes + 255) & ~(size_t)255; return p;
    };
    int*   route_c = (int*)carve(NTOK * 4);
    float* pmax_c  = (float*)carve(NTOK * 4);
    int*   route_u = (int*)carve(NTOK * 4);
    int*   dropped = (int*)carve(NTOK * 4);
    int*   counts  = (int*)carve(8 * 4);
    int*   offAll  = (int*)carve(9 * 4);
    int*   cur     = (int*)carve(8 * 4);
    int*   ntot    = (int*)carve(4);
    int*   perm    = (int*)carve(NPOS * 4);
    int*   invC    = (int*)carve(NTOK * 4);
    int*   invU    = (int*)carve(NTOK * 4);
    int*   tab     = (int*)carve(MAXT * 2 * 4);
    unsigned short* X   = (unsigned short*)carve((size_t)NPOS * HDIM * 2);
    unsigned short* G   = (unsigned short*)carve((size_t)NPOS * FDIM * 2);
    float*          Y2  = (float*)carve((size_t)2 * NPOS * HDIM * 4);
    unsigned short* BtA = (unsigned short*)carve((size_t)8 * HDIM * FDIM * 2);
    unsigned short* BtB = (unsigned short*)carve((size_t)8 * FDIM * HDIM * 2);

    int capacity = NTOK / NEXP;   // int(1.0 * 4096 / 4) = 1024

    route_kernel<<<NTOK/4, 256, 0, stream>>>(h, Wsc, bsc, Wsu, bsu,
                                             route_c, pmax_c, route_u, counts);
    rank_kernel<<<NTOK/4, 256, 0, stream>>>(route_c, route_u, pmax_c,
                                            dropped, counts, capacity);
    offsets_kernel<<<1, 64, 0, stream>>>(counts, offAll, cur, tab, ntot);
    scatter_kernel<<<NTOK/256, 256, 0, stream>>>(route_c, route_u, dropped,
                                                 offAll, cur, perm, invC, invU);
    gather_kernel<<<NPOS, 192, 0, stream>>>(h, perm, ntot, X);

    // transpose+convert weights to bf16 [8][N][K] (c experts z<4, u experts z>=4)
    wtrans_kernel<<<dim3(FDIM/64, HDIM/128, 8), 256, 0, stream>>>(W1c, W1u, BtA, HDIM, FDIM);
    wtrans_kernel<<<dim3(HDIM/64, FDIM/128, 8), 256, 0, stream>>>(W2c, W2u, BtB, FDIM, HDIM);

    // FFN1 over 8 groups: X @ W1 -> GELU -> G (bf16, position-indexed)
    ffn_gemm<<<dim3(FDIM/64, MAXT, 1), 256, 0, stream>>>(
        X, BtA, b1c, b1u, offAll, tab, G, nullptr, HDIM, FDIM, 1);
    // FFN2: G @ W2 -> Y2[z][pos][H] (fp32 slabs, split-K=2, no atomics)
    ffn_gemm<<<dim3(HDIM/64, MAXT, 2), 256, 0, stream>>>(
        G, BtB, b2c, b2u, offAll, tab, nullptr, Y2, FDIM, HDIM, 0);
    // out[tok] = sum of slabs at common pos (+ unique pos if dropped)
    combine_kernel<<<NTOK, 192, 0, stream>>>(Y2, invC, invU, dropped, out);
}